// Round 5
// baseline (874.297 us; speedup 1.0000x reference)
//
#include <hip/hip_runtime.h>
#include <hip/hip_bf16.h>

typedef unsigned int u32;

#define NN 50000
#define EE 800000
#define TT 3

// ws layout (dword offsets) — total 6,301,748 dwords = 25.2 MiB
#define OFF_C1     0         // 1536 f
#define OFF_C2     1536      // 192 f
#define OFF_CNT    1728      // 50000 i  (zeroed each call)
#define OFF_ROWPTR 51728     // 50004 i
#define OFF_CNT2   101732    // 50000 i
#define OFF_PSRC   151732    // 800000 i (src | etype<<20, dst-sorted)
#define OFF_EP     951732    // N*24 f = 1,200,000 (16B-aligned)
#define OFF_EG     2151732   // N*3 f = 150,000
#define OFF_H      2301732   // N*64 f (16B-aligned)
#define OFF_H2     5501732   // N*16 f (16B-aligned)
#define OFF_OACC   6301732   // 16 f

__global__ void zero_k(int* wsi, float* ws) {
    int i = blockIdx.x * 256 + threadIdx.x;
    if (i < NN) wsi[OFF_CNT + i] = 0;
    if (i < 16) ws[OFF_OACC + i] = 0.f;
}

// C1[t][k][h] = sum_k2 W1[t][k][k2] * sum_j (al1+ar1)[t][k2][h*8+j]
// c2[t][k]   = sum_k2 W2[t][k][k2] * sum_j (al2+ar2)[t][k2][j]
__global__ void precompute(const float* __restrict__ W1, const float* __restrict__ al1,
                           const float* __restrict__ ar1, const float* __restrict__ W2,
                           const float* __restrict__ al2, const float* __restrict__ ar2,
                           float* __restrict__ ws) {
    __shared__ float a1c[64][8];
    __shared__ float a2c[16];
    int t = blockIdx.x;
    int tid = threadIdx.x;
    {
        int k2 = tid >> 3, hh = tid & 7;
        float s = 0.f;
#pragma unroll
        for (int j = 0; j < 8; ++j) {
            int idx = t * 4096 + k2 * 64 + hh * 8 + j;
            s += al1[idx] + ar1[idx];
        }
        a1c[k2][hh] = s;
    }
    if (tid < 16) {
        float s = 0.f;
#pragma unroll
        for (int j = 0; j < 16; ++j) {
            int idx = t * 256 + tid * 16 + j;
            s += al2[idx] + ar2[idx];
        }
        a2c[tid] = s;
    }
    __syncthreads();
    {
        int k = tid >> 3, hh = tid & 7;
        float s = 0.f;
#pragma unroll
        for (int k2 = 0; k2 < 64; ++k2)
            s += W1[t * 4096 + k * 64 + k2] * a1c[k2][hh];
        ws[OFF_C1 + t * 512 + k * 8 + hh] = s;
    }
    if (tid < 64) {
        float s = 0.f;
#pragma unroll
        for (int k2 = 0; k2 < 16; ++k2)
            s += W2[t * 1024 + tid * 16 + k2] * a2c[k2];
        ws[OFF_C2 + t * 64 + tid] = s;
    }
}

__global__ __launch_bounds__(256) void hist_k(const int* __restrict__ dst, int* wsi) {
    int e = blockIdx.x * 256 + threadIdx.x;
    if (e < EE) atomicAdd(wsi + OFF_CNT + dst[e], 1);
}

// single-block exclusive scan of cnt -> rowptr (and cnt2 = rowptr copy for scatter)
__global__ __launch_bounds__(1024) void scan_k(int* wsi) {
    __shared__ int ps[1024];
    const int CH = 49;  // 1024*49 >= 50000
    int tid = threadIdx.x;
    int base = tid * CH;
    int sum = 0;
    for (int j = 0; j < CH; ++j) {
        int idx = base + j;
        if (idx < NN) sum += wsi[OFF_CNT + idx];
    }
    ps[tid] = sum;
    __syncthreads();
    for (int off = 1; off < 1024; off <<= 1) {
        int v = (tid >= off) ? ps[tid - off] : 0;
        __syncthreads();
        ps[tid] += v;
        __syncthreads();
    }
    int run = ps[tid] - sum;  // exclusive prefix
    for (int j = 0; j < CH; ++j) {
        int idx = base + j;
        if (idx < NN) {
            wsi[OFF_ROWPTR + idx] = run;
            wsi[OFF_CNT2 + idx] = run;
            run += wsi[OFF_CNT + idx];
        }
    }
    if (tid == 1023) wsi[OFF_ROWPTR + NN] = EE;
}

__global__ __launch_bounds__(256) void scatter_k(const int* __restrict__ src, const int* __restrict__ dst,
                          const int* __restrict__ etype, int* wsi) {
    int e = blockIdx.x * 256 + threadIdx.x;
    if (e >= EE) return;
    int d = dst[e];
    int slot = atomicAdd(wsi + OFF_CNT2 + d, 1);
    wsi[OFF_PSRC + slot] = src[e] | (etype[e] << 20);
}

// EP[n][t*8+h] = exp(leaky(x[n] . C1[t][:,h])) — tall-skinny GEMM 50000x24, K=64
__global__ __launch_bounds__(256) void gemm_p(const float* __restrict__ x, float* __restrict__ ws) {
    __shared__ alignas(16) float Xs[64 * 64];
    __shared__ float Cs[64 * 24];
    int tid = threadIdx.x;
    int n0 = blockIdx.x * 64;
    const float4* xg = (const float4*)(x + (size_t)n0 * 64);
    float4* xs4 = (float4*)Xs;
    for (int q = tid; q < 1024; q += 256) {
        int row = n0 + (q >> 4);
        if (row < NN) xs4[q] = xg[q];
        else xs4[q] = make_float4(0.f, 0.f, 0.f, 0.f);
    }
    for (int q = tid; q < 1536; q += 256) {
        int k = q / 24, j = q - k * 24;
        Cs[q] = ws[OFF_C1 + (j >> 3) * 512 + k * 8 + (j & 7)];
    }
    __syncthreads();
    for (int o = tid; o < 1536; o += 256) {
        int n = o / 24, j = o - n * 24;
        if (n0 + n >= NN) break;
        float acc = 0.f;
#pragma unroll
        for (int k = 0; k < 64; ++k) acc += Xs[n * 64 + k] * Cs[k * 24 + j];
        float v = acc > 0.f ? acc : 0.2f * acc;
        ws[OFF_EP + (size_t)(n0 + n) * 24 + j] = __expf(v);
    }
}

// layer0 fused softmax+aggregate: one wave per dst, lane = output channel.
// y[t][h] per lane(k) accumulated in regs; GEMV vs LDS-staged W1 once per dst.
// Also emits EG[d][t] = exp(leaky(H[d] . c2[t])) for layer 2.
__global__ __launch_bounds__(256) void agg1(const float* __restrict__ x, const float* __restrict__ W1,
                     const int* __restrict__ wsi, float* __restrict__ ws) {
    __shared__ alignas(16) float W1s[12288];     // 48 KB, [t][k][c]
    __shared__ alignas(16) float ys[4][24 * 64]; // 24.6 KB
    __shared__ float c2s[192];
    int tid = threadIdx.x;
    for (int q = tid; q < 12288; q += 256) W1s[q] = W1[q];
    if (tid < 192) c2s[tid] = ws[OFF_C2 + tid];
    __syncthreads();
    int wave = tid >> 6, lane = tid & 63;
    int d = blockIdx.x * 4 + wave;
    int start = wsi[OFF_ROWPTR + d], end = wsi[OFF_ROWPTR + d + 1];
    float y[3][8];
    float den[8];
#pragma unroll
    for (int t = 0; t < 3; ++t)
#pragma unroll
        for (int h = 0; h < 8; ++h) y[t][h] = 0.f;
#pragma unroll
    for (int h = 0; h < 8; ++h) den[h] = 0.f;
    const float4* epb = (const float4*)(ws + OFF_EP);
    for (int s = start; s < end; ++s) {
        int p = wsi[OFF_PSRC + s];
        int sn = p & 0xFFFFF, t = p >> 20;
        float m = x[(size_t)sn * 64 + lane];
        const float4* ep = epb + (size_t)sn * 6 + t * 2;
        float4 e0 = ep[0], e1 = ep[1];
        float w[8] = {e0.x, e0.y, e0.z, e0.w, e1.x, e1.y, e1.z, e1.w};
#pragma unroll
        for (int h = 0; h < 8; ++h) den[h] += w[h];
        if (t == 0) {
#pragma unroll
            for (int h = 0; h < 8; ++h) y[0][h] += w[h] * m;
        } else if (t == 1) {
#pragma unroll
            for (int h = 0; h < 8; ++h) y[1][h] += w[h] * m;
        } else {
#pragma unroll
            for (int h = 0; h < 8; ++h) y[2][h] += w[h] * m;
        }
    }
    bool has = end > start;
    float inv[8];
#pragma unroll
    for (int h = 0; h < 8; ++h) inv[h] = has ? 1.f / den[h] : 0.f;
    float* my = ys[wave];
#pragma unroll
    for (int t = 0; t < 3; ++t)
#pragma unroll
        for (int h = 0; h < 8; ++h) my[(t * 8 + h) * 64 + lane] = y[t][h] * inv[h];
    // epilogue: out_c = sum_t sum_k yn[t][h(c)][k] * W1[t][k][c]  (own wave's LDS, no barrier)
    int h = lane >> 3;
    float acc = 0.f;
#pragma unroll
    for (int t = 0; t < 3; ++t) {
        const float* yt = my + (t * 8 + h) * 64;
        const float* Wt = W1s + t * 4096 + lane;
#pragma unroll
        for (int k4 = 0; k4 < 16; ++k4) {
            float4 y4 = *(const float4*)(yt + k4 * 4);
            acc += y4.x * Wt[(k4 * 4 + 0) * 64];
            acc += y4.y * Wt[(k4 * 4 + 1) * 64];
            acc += y4.z * Wt[(k4 * 4 + 2) * 64];
            acc += y4.w * Wt[(k4 * 4 + 3) * 64];
        }
    }
    float v = acc > 0.f ? acc : __expf(acc) - 1.f;  // ELU fused (empty dst: acc=0 -> 0)
    ws[OFF_H + (size_t)d * 64 + lane] = v;
    // EG[d][t] = exp(leaky(H[d] . c2[t])) via wave butterfly
    float eg[3];
#pragma unroll
    for (int t = 0; t < 3; ++t) {
        float pr = v * c2s[t * 64 + lane];
#pragma unroll
        for (int mask = 1; mask < 64; mask <<= 1) pr += __shfl_xor(pr, mask);
        pr = pr > 0.f ? pr : 0.2f * pr;
        eg[t] = __expf(pr);
    }
    if (lane == 0) {
        float* egp = ws + OFF_EG + (size_t)d * 3;
        egp[0] = eg[0]; egp[1] = eg[1]; egp[2] = eg[2];
    }
}

// h2[i][c] = res_b[c] + sum_k h[i][k] * res_w[k][c]   (residual pre-pass, all nodes)
__global__ __launch_bounds__(256) void resid_k(const float* __restrict__ res_w, const float* __restrict__ res_b,
                        float* __restrict__ ws) {
    __shared__ alignas(16) float Wr[1024];
    __shared__ float Br[16];
    int tid = threadIdx.x;
    for (int q = tid; q < 1024; q += 256) Wr[q] = res_w[q];
    if (tid < 16) Br[tid] = res_b[tid];
    __syncthreads();
    int g = blockIdx.x * 256 + tid;
    if (g >= NN * 16) return;
    int i = g >> 4, c = g & 15;
    const float4* hr = (const float4*)(ws + OFF_H + (size_t)i * 64);
    float acc = Br[c];
#pragma unroll
    for (int k4 = 0; k4 < 16; ++k4) {
        float4 h4 = hr[k4];
        acc += h4.x * Wr[(k4*4+0)*16 + c];
        acc += h4.y * Wr[(k4*4+1)*16 + c];
        acc += h4.z * Wr[(k4*4+2)*16 + c];
        acc += h4.w * Wr[(k4*4+3)*16 + c];
    }
    ws[OFF_H2 + g] = acc;
}

// layer1 fused: one wave per dst; per-edge weight from EG; adds into resid H2.
__global__ __launch_bounds__(256) void agg2(const float* __restrict__ W2, const int* __restrict__ wsi,
                     float* __restrict__ ws) {
    __shared__ alignas(16) float ys2[4][3 * 64];
    __shared__ alignas(16) float Wls[3072];
    int tid = threadIdx.x;
    for (int q = tid; q < 3072; q += 256) Wls[q] = W2[q];
    __syncthreads();
    int wave = tid >> 6, lane = tid & 63;
    int d = blockIdx.x * 4 + wave;
    int start = wsi[OFF_ROWPTR + d], end = wsi[OFF_ROWPTR + d + 1];
    if (end <= start) return;  // H2 row stays = residual (matches segment_sum=0)
    float y0 = 0.f, y1 = 0.f, y2 = 0.f, den = 0.f;
    for (int s = start; s < end; ++s) {
        int p = wsi[OFF_PSRC + s];
        int sn = p & 0xFFFFF, t = p >> 20;
        float m = ws[OFF_H + (size_t)sn * 64 + lane];
        float w = ws[OFF_EG + (size_t)sn * 3 + t];
        den += w;
        if (t == 0) y0 += w * m;
        else if (t == 1) y1 += w * m;
        else y2 += w * m;
    }
    float* my = ys2[wave];
    my[0 * 64 + lane] = y0;
    my[1 * 64 + lane] = y1;
    my[2 * 64 + lane] = y2;
    int q = lane >> 4, c = lane & 15;
    float acc = 0.f;
#pragma unroll
    for (int t = 0; t < 3; ++t) {
#pragma unroll
        for (int kk = 0; kk < 4; ++kk) {
            float4 y4 = *(const float4*)(my + t * 64 + q * 16 + kk * 4);
            const float* Wt = Wls + t * 1024 + (q * 16 + kk * 4) * 16 + c;
            acc += y4.x * Wt[0];
            acc += y4.y * Wt[16];
            acc += y4.z * Wt[32];
            acc += y4.w * Wt[48];
        }
    }
    acc += __shfl_xor(acc, 16);
    acc += __shfl_xor(acc, 32);
    if (q == 0) {
        float* o = ws + OFF_H2 + (size_t)d * 16 + c;
        *o = *o + acc / den;
    }
}

__global__ void mean_k(float* ws) {
    __shared__ float part[16][17];
    int tid = threadIdx.x;
    int c = tid & 15, r = tid >> 4;
    float s = 0.f;
    for (int i = blockIdx.x * 16 + r; i < NN; i += gridDim.x * 16)
        s += ws[OFF_H2 + (size_t)i * 16 + c];
    part[r][c] = s;
    __syncthreads();
    if (tid < 16) {
        float t = 0.f;
#pragma unroll
        for (int r2 = 0; r2 < 16; ++r2) t += part[r2][tid];
        atomicAdd(ws + OFF_OACC + tid, t);
    }
}

__global__ void final_k(float* ws, float* out) {
    int c = threadIdx.x;
    if (c < 16) out[c] = ws[OFF_OACC + c] * (1.0f / (float)NN);
}

extern "C" void kernel_launch(void* const* d_in, const int* in_sizes, int n_in,
                              void* d_out, int out_size, void* d_ws, size_t ws_size,
                              hipStream_t stream) {
    const float* x     = (const float*)d_in[0];
    const int*   src   = (const int*)d_in[1];
    const int*   dst   = (const int*)d_in[2];
    // d_in[3] = ntype (unused by reference)
    const int*   etype = (const int*)d_in[4];
    const float* W1    = (const float*)d_in[5];
    const float* al1   = (const float*)d_in[6];
    const float* ar1   = (const float*)d_in[7];
    const float* W2    = (const float*)d_in[8];
    const float* al2   = (const float*)d_in[9];
    const float* ar2   = (const float*)d_in[10];
    const float* res_w = (const float*)d_in[11];
    const float* res_b = (const float*)d_in[12];
    float* ws = (float*)d_ws;
    int* wsi = (int*)d_ws;
    float* out = (float*)d_out;

    hipLaunchKernelGGL(zero_k, dim3((NN + 255) / 256), dim3(256), 0, stream, wsi, ws);
    hipLaunchKernelGGL(precompute, dim3(TT), dim3(512), 0, stream, W1, al1, ar1, W2, al2, ar2, ws);
    hipLaunchKernelGGL(hist_k, dim3((EE + 255) / 256), dim3(256), 0, stream, dst, wsi);
    hipLaunchKernelGGL(scan_k, dim3(1), dim3(1024), 0, stream, wsi);
    hipLaunchKernelGGL(scatter_k, dim3((EE + 255) / 256), dim3(256), 0, stream, src, dst, etype, wsi);
    hipLaunchKernelGGL(gemm_p, dim3((NN + 63) / 64), dim3(256), 0, stream, x, ws);
    hipLaunchKernelGGL(agg1, dim3(NN / 4), dim3(256), 0, stream, x, W1, wsi, ws);
    hipLaunchKernelGGL(resid_k, dim3(NN * 16 / 256), dim3(256), 0, stream, res_w, res_b, ws);
    hipLaunchKernelGGL(agg2, dim3(NN / 4), dim3(256), 0, stream, W2, wsi, ws);
    hipLaunchKernelGGL(mean_k, dim3(256), dim3(256), 0, stream, ws);
    hipLaunchKernelGGL(final_k, dim3(1), dim3(64), 0, stream, ws, out);
}

// Round 6
// 545.957 us; speedup vs baseline: 1.6014x; 1.6014x over previous
//
#include <hip/hip_runtime.h>
#include <hip/hip_bf16.h>

typedef unsigned int u32;

#define NN 50000
#define EE 800000
#define TT 3

// ws layout (dword offsets) — total 5,503,012 dwords = 22.0 MiB
#define OFF_C1     0         // 1536 f
#define OFF_C2     1536      // 192 f
#define OFF_CNT    1728      // 50000 i (zeroed each call)
#define OFF_ROWPTR 51728     // 50004 i
#define OFF_CNT2   101732    // 50000 i
#define OFF_BSUM   151732    // 256 i
#define OFF_PSRC   151988    // 800000 i (src | etype<<20, dst-sorted)
#define OFF_EP     951988    // N*24 f (16B-aligned)
#define OFF_EG     2151988   // N*3 f
#define OFF_H      2301988   // N*64 f (16B-aligned)
#define OFF_OPART  5501988   // 64*16 f (zeroed each call)

__global__ __launch_bounds__(256) void zero_k(int* wsi, float* ws) {
    int i = blockIdx.x * 256 + threadIdx.x;
    if (i < NN) wsi[OFF_CNT + i] = 0;
    if (i < 1024) ws[OFF_OPART + i] = 0.f;
}

// C1[t][k][h] = sum_k2 W1[t][k][k2] * sum_j (al1+ar1)[t][k2][h*8+j]
// c2[t][k]   = sum_k2 W2[t][k][k2] * sum_j (al2+ar2)[t][k2][j]
__global__ void precompute(const float* __restrict__ W1, const float* __restrict__ al1,
                           const float* __restrict__ ar1, const float* __restrict__ W2,
                           const float* __restrict__ al2, const float* __restrict__ ar2,
                           float* __restrict__ ws) {
    __shared__ float a1c[64][8];
    __shared__ float a2c[16];
    int t = blockIdx.x;
    int tid = threadIdx.x;
    {
        int k2 = tid >> 3, hh = tid & 7;
        float s = 0.f;
#pragma unroll
        for (int j = 0; j < 8; ++j) {
            int idx = t * 4096 + k2 * 64 + hh * 8 + j;
            s += al1[idx] + ar1[idx];
        }
        a1c[k2][hh] = s;
    }
    if (tid < 16) {
        float s = 0.f;
#pragma unroll
        for (int j = 0; j < 16; ++j) {
            int idx = t * 256 + tid * 16 + j;
            s += al2[idx] + ar2[idx];
        }
        a2c[tid] = s;
    }
    __syncthreads();
    {
        int k = tid >> 3, hh = tid & 7;
        float s = 0.f;
#pragma unroll
        for (int k2 = 0; k2 < 64; ++k2)
            s += W1[t * 4096 + k * 64 + k2] * a1c[k2][hh];
        ws[OFF_C1 + t * 512 + k * 8 + hh] = s;
    }
    if (tid < 64) {
        float s = 0.f;
#pragma unroll
        for (int k2 = 0; k2 < 16; ++k2)
            s += W2[t * 1024 + tid * 16 + k2] * a2c[k2];
        ws[OFF_C2 + t * 64 + tid] = s;
    }
}

__global__ __launch_bounds__(256) void hist_k(const int* __restrict__ dst, int* wsi) {
    int e = blockIdx.x * 256 + threadIdx.x;
    if (e < EE) atomicAdd(wsi + OFF_CNT + dst[e], 1);
}

// 3-phase multi-block exclusive scan of cnt -> rowptr (+ cnt2 copy)
__global__ __launch_bounds__(256) void scan1(int* wsi) {
    __shared__ int sd[256];
    int t = threadIdx.x;
    int i = blockIdx.x * 256 + t;
    int v = (i < NN) ? wsi[OFF_CNT + i] : 0;
    sd[t] = v;
    __syncthreads();
    for (int o = 128; o > 0; o >>= 1) {
        if (t < o) sd[t] += sd[t + o];
        __syncthreads();
    }
    if (t == 0) wsi[OFF_BSUM + blockIdx.x] = sd[0];
}

__global__ __launch_bounds__(256) void scan2(int* wsi) {
    __shared__ int sd[256];
    int t = threadIdx.x;
    int v = (t < 196) ? wsi[OFF_BSUM + t] : 0;
    sd[t] = v;
    __syncthreads();
    for (int o = 1; o < 256; o <<= 1) {
        int u = (t >= o) ? sd[t - o] : 0;
        __syncthreads();
        sd[t] += u;
        __syncthreads();
    }
    wsi[OFF_BSUM + t] = sd[t] - v;  // exclusive
    if (t == 0) wsi[OFF_ROWPTR + NN] = EE;
}

__global__ __launch_bounds__(256) void scan3(int* wsi) {
    __shared__ int sd[256];
    int t = threadIdx.x;
    int i = blockIdx.x * 256 + t;
    int v = (i < NN) ? wsi[OFF_CNT + i] : 0;
    sd[t] = v;
    __syncthreads();
    for (int o = 1; o < 256; o <<= 1) {
        int u = (t >= o) ? sd[t - o] : 0;
        __syncthreads();
        sd[t] += u;
        __syncthreads();
    }
    if (i < NN) {
        int ex = wsi[OFF_BSUM + blockIdx.x] + sd[t] - v;
        wsi[OFF_ROWPTR + i] = ex;
        wsi[OFF_CNT2 + i] = ex;
    }
}

__global__ __launch_bounds__(256) void scatter_k(const int* __restrict__ src, const int* __restrict__ dst,
                          const int* __restrict__ etype, int* wsi) {
    int e = blockIdx.x * 256 + threadIdx.x;
    if (e >= EE) return;
    int d = dst[e];
    int slot = atomicAdd(wsi + OFF_CNT2 + d, 1);
    wsi[OFF_PSRC + slot] = src[e] | (etype[e] << 20);
}

// EP[n][t*8+h] = exp(leaky(x[n] . C1[t][:,h])) — tall-skinny GEMM 50000x24, K=64
__global__ __launch_bounds__(256) void gemm_p(const float* __restrict__ x, float* __restrict__ ws) {
    __shared__ alignas(16) float Xs[64 * 64];
    __shared__ float Cs[64 * 24];
    int tid = threadIdx.x;
    int n0 = blockIdx.x * 64;
    const float4* xg = (const float4*)(x + (size_t)n0 * 64);
    float4* xs4 = (float4*)Xs;
    for (int q = tid; q < 1024; q += 256) {
        int row = n0 + (q >> 4);
        if (row < NN) xs4[q] = xg[q];
        else xs4[q] = make_float4(0.f, 0.f, 0.f, 0.f);
    }
    for (int q = tid; q < 1536; q += 256) {
        int k = q / 24, j = q - k * 24;
        Cs[q] = ws[OFF_C1 + (j >> 3) * 512 + k * 8 + (j & 7)];
    }
    __syncthreads();
    for (int o = tid; o < 1536; o += 256) {
        int n = o / 24, j = o - n * 24;
        if (n0 + n >= NN) break;
        float acc = 0.f;
#pragma unroll
        for (int k = 0; k < 64; ++k) acc += Xs[n * 64 + k] * Cs[k * 24 + j];
        float v = acc > 0.f ? acc : 0.2f * acc;
        ws[OFF_EP + (size_t)(n0 + n) * 24 + j] = __expf(v);
    }
}

// layer0 fused softmax+aggregate: one wave per dst, lane = channel/k.
// Main loop software-pipelined 1 deep; epilogue GEMV reads W1 from L2.
// Emits H[d][:] (ELU'd) and EG[d][t] for layer 2.
__global__ __launch_bounds__(256) void agg1(const float* __restrict__ x, const float* __restrict__ W1,
                     const int* __restrict__ wsi, float* __restrict__ ws) {
    __shared__ alignas(16) float ys[4][24 * 72];  // 27648 B, stride 72 = conflict-free
    __shared__ float c2s[192];
    int tid = threadIdx.x;
    if (tid < 192) c2s[tid] = ws[OFF_C2 + tid];
    int wave = tid >> 6, lane = tid & 63;
    int d = blockIdx.x * 4 + wave;
    int start = wsi[OFF_ROWPTR + d], end = wsi[OFF_ROWPTR + d + 1];
    float y[3][8];
    float den[8];
#pragma unroll
    for (int t = 0; t < 3; ++t)
#pragma unroll
        for (int h = 0; h < 8; ++h) y[t][h] = 0.f;
#pragma unroll
    for (int h = 0; h < 8; ++h) den[h] = 0.f;
    const float4* epb = (const float4*)(ws + OFF_EP);
    float m_c = 0.f;
    float4 e0_c = make_float4(0,0,0,0), e1_c = make_float4(0,0,0,0);
    int t_c = 0;
    if (start < end) {
        int p = wsi[OFF_PSRC + start];
        int sn = p & 0xFFFFF; t_c = p >> 20;
        m_c = x[(size_t)sn * 64 + lane];
        const float4* ep = epb + (size_t)sn * 6 + t_c * 2;
        e0_c = ep[0]; e1_c = ep[1];
    }
    for (int s = start; s < end; ++s) {
        int t = t_c; float m = m_c; float4 e0 = e0_c, e1 = e1_c;
        if (s + 1 < end) {  // prefetch next edge before this edge's FMAs
            int p = wsi[OFF_PSRC + s + 1];
            int sn = p & 0xFFFFF; t_c = p >> 20;
            m_c = x[(size_t)sn * 64 + lane];
            const float4* ep = epb + (size_t)sn * 6 + t_c * 2;
            e0_c = ep[0]; e1_c = ep[1];
        }
        float w[8] = {e0.x, e0.y, e0.z, e0.w, e1.x, e1.y, e1.z, e1.w};
#pragma unroll
        for (int h = 0; h < 8; ++h) den[h] += w[h];
        if (t == 0) {
#pragma unroll
            for (int h = 0; h < 8; ++h) y[0][h] += w[h] * m;
        } else if (t == 1) {
#pragma unroll
            for (int h = 0; h < 8; ++h) y[1][h] += w[h] * m;
        } else {
#pragma unroll
            for (int h = 0; h < 8; ++h) y[2][h] += w[h] * m;
        }
    }
    float* my = ys[wave];
#pragma unroll
    for (int t = 0; t < 3; ++t)
#pragma unroll
        for (int h = 0; h < 8; ++h) my[(t * 8 + h) * 72 + lane] = y[t][h];
    __syncthreads();  // align waves so all 4 stream W1 together (L1 locality)
    int h = lane >> 3;
    float acc = 0.f;
#pragma unroll
    for (int t = 0; t < 3; ++t) {
        const float* yt = my + (t * 8 + h) * 72;
        const float* Wt = W1 + t * 4096 + lane;
#pragma unroll
        for (int k4 = 0; k4 < 16; ++k4) {
            float4 y4 = *(const float4*)(yt + k4 * 4);
            acc += y4.x * Wt[(k4 * 4 + 0) * 64];
            acc += y4.y * Wt[(k4 * 4 + 1) * 64];
            acc += y4.z * Wt[(k4 * 4 + 2) * 64];
            acc += y4.w * Wt[(k4 * 4 + 3) * 64];
        }
    }
    float dn = den[0];
    if (h == 1) dn = den[1];
    if (h == 2) dn = den[2];
    if (h == 3) dn = den[3];
    if (h == 4) dn = den[4];
    if (h == 5) dn = den[5];
    if (h == 6) dn = den[6];
    if (h == 7) dn = den[7];
    float v = (end > start) ? acc / dn : 0.f;
    v = v > 0.f ? v : __expf(v) - 1.f;  // ELU fused
    ws[OFF_H + (size_t)d * 64 + lane] = v;
    // EG[d][t] = exp(leaky(H[d] . c2[t])) via wave butterfly
    float eg[3];
#pragma unroll
    for (int t = 0; t < 3; ++t) {
        float pr = v * c2s[t * 64 + lane];
#pragma unroll
        for (int mask = 1; mask < 64; mask <<= 1) pr += __shfl_xor(pr, mask);
        pr = pr > 0.f ? pr : 0.2f * pr;
        eg[t] = __expf(pr);
    }
    if (lane == 0) {
        float* egp = ws + OFF_EG + (size_t)d * 3;
        egp[0] = eg[0]; egp[1] = eg[1]; egp[2] = eg[2];
    }
}

// layer1 fused: attention + residual + global-mean partial. One wave per dst.
__global__ __launch_bounds__(256) void agg2(const float* __restrict__ W2, const float* __restrict__ res_w,
                     const float* __restrict__ res_b, const int* __restrict__ wsi,
                     float* __restrict__ ws) {
    __shared__ alignas(16) float Wls[3072];
    __shared__ alignas(16) float Wrs[1024];
    __shared__ float Brs[16];
    __shared__ alignas(16) float ys2[4][4 * 72];
    __shared__ float outs[4][16];
    int tid = threadIdx.x;
    for (int q = tid; q < 3072; q += 256) Wls[q] = W2[q];
    for (int q = tid; q < 1024; q += 256) Wrs[q] = res_w[q];
    if (tid < 16) Brs[tid] = res_b[tid];
    __syncthreads();
    int wave = tid >> 6, lane = tid & 63;
    int d = blockIdx.x * 4 + wave;
    int start = wsi[OFF_ROWPTR + d], end = wsi[OFF_ROWPTR + d + 1];
    float hd = ws[OFF_H + (size_t)d * 64 + lane];
    float y0 = 0.f, y1 = 0.f, y2 = 0.f, den = 0.f;
    float m_c = 0.f, w_c = 0.f;
    int t_c = 0;
    if (start < end) {
        int p = wsi[OFF_PSRC + start];
        int sn = p & 0xFFFFF; t_c = p >> 20;
        m_c = ws[OFF_H + (size_t)sn * 64 + lane];
        w_c = ws[OFF_EG + (size_t)sn * 3 + t_c];
    }
    for (int s = start; s < end; ++s) {
        int t = t_c; float m = m_c; float w = w_c;
        if (s + 1 < end) {
            int p = wsi[OFF_PSRC + s + 1];
            int sn = p & 0xFFFFF; t_c = p >> 20;
            m_c = ws[OFF_H + (size_t)sn * 64 + lane];
            w_c = ws[OFF_EG + (size_t)sn * 3 + t_c];
        }
        den += w;
        if (t == 0) y0 += w * m;
        else if (t == 1) y1 += w * m;
        else y2 += w * m;
    }
    float* my = ys2[wave];
    my[0 * 72 + lane] = y0;
    my[1 * 72 + lane] = y1;
    my[2 * 72 + lane] = y2;
    my[3 * 72 + lane] = hd;
    int q = lane >> 4, c = lane & 15;
    float accA = 0.f, accR = 0.f;
#pragma unroll
    for (int t = 0; t < 3; ++t) {
#pragma unroll
        for (int kk = 0; kk < 4; ++kk) {
            float4 y4 = *(const float4*)(my + t * 72 + q * 16 + kk * 4);
            const float* Wt = Wls + t * 1024 + (q * 16 + kk * 4) * 16 + c;
            accA += y4.x * Wt[0];
            accA += y4.y * Wt[16];
            accA += y4.z * Wt[32];
            accA += y4.w * Wt[48];
        }
    }
#pragma unroll
    for (int kk = 0; kk < 4; ++kk) {
        float4 h4 = *(const float4*)(my + 3 * 72 + q * 16 + kk * 4);
        const float* Rt = Wrs + (q * 16 + kk * 4) * 16 + c;
        accR += h4.x * Rt[0];
        accR += h4.y * Rt[16];
        accR += h4.z * Rt[32];
        accR += h4.w * Rt[48];
    }
    accA += __shfl_xor(accA, 16);
    accA += __shfl_xor(accA, 32);
    accR += __shfl_xor(accR, 16);
    accR += __shfl_xor(accR, 32);
    if (q == 0) {
        float val = Brs[c] + accR + ((end > start) ? accA / den : 0.f);
        outs[wave][c] = val;
    }
    __syncthreads();
    if (tid < 16) {
        float s = outs[0][tid] + outs[1][tid] + outs[2][tid] + outs[3][tid];
        atomicAdd(ws + OFF_OPART + (blockIdx.x & 63) * 16 + tid, s);
    }
}

__global__ void final_k(float* ws, float* out) {
    int c = threadIdx.x;
    if (c < 16) {
        float s = 0.f;
        for (int r = 0; r < 64; ++r) s += ws[OFF_OPART + r * 16 + c];
        out[c] = s * (1.0f / (float)NN);
    }
}

extern "C" void kernel_launch(void* const* d_in, const int* in_sizes, int n_in,
                              void* d_out, int out_size, void* d_ws, size_t ws_size,
                              hipStream_t stream) {
    const float* x     = (const float*)d_in[0];
    const int*   src   = (const int*)d_in[1];
    const int*   dst   = (const int*)d_in[2];
    // d_in[3] = ntype (unused by reference)
    const int*   etype = (const int*)d_in[4];
    const float* W1    = (const float*)d_in[5];
    const float* al1   = (const float*)d_in[6];
    const float* ar1   = (const float*)d_in[7];
    const float* W2    = (const float*)d_in[8];
    const float* al2   = (const float*)d_in[9];
    const float* ar2   = (const float*)d_in[10];
    const float* res_w = (const float*)d_in[11];
    const float* res_b = (const float*)d_in[12];
    float* ws = (float*)d_ws;
    int* wsi = (int*)d_ws;
    float* out = (float*)d_out;

    hipLaunchKernelGGL(zero_k, dim3(196), dim3(256), 0, stream, wsi, ws);
    hipLaunchKernelGGL(precompute, dim3(TT), dim3(512), 0, stream, W1, al1, ar1, W2, al2, ar2, ws);
    hipLaunchKernelGGL(hist_k, dim3((EE + 255) / 256), dim3(256), 0, stream, dst, wsi);
    hipLaunchKernelGGL(scan1, dim3(196), dim3(256), 0, stream, wsi);
    hipLaunchKernelGGL(scan2, dim3(1), dim3(256), 0, stream, wsi);
    hipLaunchKernelGGL(scan3, dim3(196), dim3(256), 0, stream, wsi);
    hipLaunchKernelGGL(scatter_k, dim3((EE + 255) / 256), dim3(256), 0, stream, src, dst, etype, wsi);
    hipLaunchKernelGGL(gemm_p, dim3((NN + 63) / 64), dim3(256), 0, stream, x, ws);
    hipLaunchKernelGGL(agg1, dim3(NN / 4), dim3(256), 0, stream, x, W1, wsi, ws);
    hipLaunchKernelGGL(agg2, dim3(NN / 4), dim3(256), 0, stream, W2, res_w, res_b, wsi, ws);
    hipLaunchKernelGGL(final_k, dim3(1), dim3(64), 0, stream, ws, out);
}

// Round 7
// 410.402 us; speedup vs baseline: 2.1303x; 1.3303x over previous
//
#include <hip/hip_runtime.h>
#include <hip/hip_bf16.h>

typedef unsigned int u32;
typedef unsigned short u16;

#define NN 50000
#define EE 800000
#define TT 3

// ws layout (dword offsets) — total 10,153,012 dwords = 40.6 MiB
#define OFF_C1     0         // 1536 f
#define OFF_C2     1536      // 192 f
#define OFF_CNT    1728      // 50000 i (zeroed each call)
#define OFF_ROWPTR 51728     // 50004 i
#define OFF_CNT2   101732    // 50000 i
#define OFF_BSUM   151732    // 256 i
#define OFF_PSRC   151988    // 800000 i (src | etype<<20, dst-sorted)
#define OFF_FBF    951988    // N*192 bf16 = 4,800,000 dwords (dead after agg1)
#define OFF_F2     951988    // N*48 bf16 = 1,200,000 dwords (overlays FBF)
#define OFF_EG     2151988   // N*3 f (overlays FBF tail)
#define OFF_EP     5751988   // N*24 f
#define OFF_H      6951988   // N*64 f
#define OFF_OPART  10151988  // 64*16 f (zeroed each call)

__device__ __forceinline__ float bf2f(u32 u) {
    union { u32 i; float f; } v; v.i = u << 16; return v.f;
}
__device__ __forceinline__ u32 f2bf(float f) {  // RNE
    union { float f; u32 i; } v; v.f = f;
    return (v.i + 0x7fffu + ((v.i >> 16) & 1u)) >> 16;
}

__global__ __launch_bounds__(256) void zero_k(int* wsi, float* ws) {
    int i = blockIdx.x * 256 + threadIdx.x;
    if (i < NN) wsi[OFF_CNT + i] = 0;
    if (i < 1024) ws[OFF_OPART + i] = 0.f;
}

// C1[t][k][h] = sum_k2 W1[t][k][k2] * sum_j (al1+ar1)[t][k2][h*8+j]
// c2[t][k]   = sum_k2 W2[t][k][k2] * sum_j (al2+ar2)[t][k2][j]
__global__ void precompute(const float* __restrict__ W1, const float* __restrict__ al1,
                           const float* __restrict__ ar1, const float* __restrict__ W2,
                           const float* __restrict__ al2, const float* __restrict__ ar2,
                           float* __restrict__ ws) {
    __shared__ float a1c[64][8];
    __shared__ float a2c[16];
    int t = blockIdx.x;
    int tid = threadIdx.x;
    {
        int k2 = tid >> 3, hh = tid & 7;
        float s = 0.f;
#pragma unroll
        for (int j = 0; j < 8; ++j) {
            int idx = t * 4096 + k2 * 64 + hh * 8 + j;
            s += al1[idx] + ar1[idx];
        }
        a1c[k2][hh] = s;
    }
    if (tid < 16) {
        float s = 0.f;
#pragma unroll
        for (int j = 0; j < 16; ++j) {
            int idx = t * 256 + tid * 16 + j;
            s += al2[idx] + ar2[idx];
        }
        a2c[tid] = s;
    }
    __syncthreads();
    {
        int k = tid >> 3, hh = tid & 7;
        float s = 0.f;
#pragma unroll
        for (int k2 = 0; k2 < 64; ++k2)
            s += W1[t * 4096 + k * 64 + k2] * a1c[k2][hh];
        ws[OFF_C1 + t * 512 + k * 8 + hh] = s;
    }
    if (tid < 64) {
        float s = 0.f;
#pragma unroll
        for (int k2 = 0; k2 < 16; ++k2)
            s += W2[t * 1024 + tid * 16 + k2] * a2c[k2];
        ws[OFF_C2 + t * 64 + tid] = s;
    }
}

__global__ __launch_bounds__(256) void hist_k(const int* __restrict__ dst, int* wsi) {
    int e = blockIdx.x * 256 + threadIdx.x;
    if (e < EE) atomicAdd(wsi + OFF_CNT + dst[e], 1);
}

__global__ __launch_bounds__(256) void scan1(int* wsi) {
    __shared__ int sd[256];
    int t = threadIdx.x;
    int i = blockIdx.x * 256 + t;
    int v = (i < NN) ? wsi[OFF_CNT + i] : 0;
    sd[t] = v;
    __syncthreads();
    for (int o = 128; o > 0; o >>= 1) {
        if (t < o) sd[t] += sd[t + o];
        __syncthreads();
    }
    if (t == 0) wsi[OFF_BSUM + blockIdx.x] = sd[0];
}

__global__ __launch_bounds__(256) void scan2(int* wsi) {
    __shared__ int sd[256];
    int t = threadIdx.x;
    int v = (t < 196) ? wsi[OFF_BSUM + t] : 0;
    sd[t] = v;
    __syncthreads();
    for (int o = 1; o < 256; o <<= 1) {
        int u = (t >= o) ? sd[t - o] : 0;
        __syncthreads();
        sd[t] += u;
        __syncthreads();
    }
    wsi[OFF_BSUM + t] = sd[t] - v;  // exclusive
    if (t == 0) wsi[OFF_ROWPTR + NN] = EE;
}

__global__ __launch_bounds__(256) void scan3(int* wsi) {
    __shared__ int sd[256];
    int t = threadIdx.x;
    int i = blockIdx.x * 256 + t;
    int v = (i < NN) ? wsi[OFF_CNT + i] : 0;
    sd[t] = v;
    __syncthreads();
    for (int o = 1; o < 256; o <<= 1) {
        int u = (t >= o) ? sd[t - o] : 0;
        __syncthreads();
        sd[t] += u;
        __syncthreads();
    }
    if (i < NN) {
        int ex = wsi[OFF_BSUM + blockIdx.x] + sd[t] - v;
        wsi[OFF_ROWPTR + i] = ex;
        wsi[OFF_CNT2 + i] = ex;
    }
}

__global__ __launch_bounds__(256) void scatter_k(const int* __restrict__ src, const int* __restrict__ dst,
                          const int* __restrict__ etype, int* wsi) {
    int e = blockIdx.x * 256 + threadIdx.x;
    if (e >= EE) return;
    int d = dst[e];
    int slot = atomicAdd(wsi + OFF_CNT2 + d, 1);
    wsi[OFF_PSRC + slot] = src[e] | (etype[e] << 20);
}

// F[n][t][c] = x[n].W1[t][:,c]  (bf16)  and  EP[n][t*8+h] = exp(leaky(x[n].C1[t][:,h]))
// 224 staged cols: 0..191 = F, 192..215 = EP logits, 216..223 dummy.
__global__ __launch_bounds__(256) void gemm_f(const float* __restrict__ x, const float* __restrict__ W1,
                       float* __restrict__ ws) {
    __shared__ alignas(16) float CW[64 * 224];  // 57.3 KB
    __shared__ alignas(16) float Xs[64 * 65];   // 16.6 KB
    int tid = threadIdx.x;
    int n0 = blockIdx.x * 64;
    for (int q = tid; q < 14336; q += 256) {
        int k = q / 224, c = q - k * 224;
        float v;
        if (c < 192) v = W1[(c >> 6) * 4096 + k * 64 + (c & 63)];
        else if (c < 216) v = ws[OFF_C1 + ((c - 192) >> 3) * 512 + k * 8 + ((c - 192) & 7)];
        else v = 0.f;
        CW[k * 224 + c] = v;
    }
    {
        const float4* xg = (const float4*)(x + (size_t)n0 * 64);
        for (int q = tid; q < 1024; q += 256) {
            int row = q >> 4;
            float4 v = (n0 + row < NN) ? xg[q] : make_float4(0.f, 0.f, 0.f, 0.f);
            *(float4*)(Xs + row * 65 + (q & 15) * 4) = v;
        }
    }
    __syncthreads();
    int node = tid >> 2, cb = tid & 3;
    int cbase = cb * 56;
    float4 acc4[14];
#pragma unroll
    for (int i = 0; i < 14; ++i) acc4[i] = make_float4(0.f, 0.f, 0.f, 0.f);
    const float* xrow = Xs + node * 65;
    for (int k = 0; k < 64; ++k) {
        float xv = xrow[k];
        const float4* cw4 = (const float4*)(CW + k * 224 + cbase);
#pragma unroll
        for (int i = 0; i < 14; ++i) {
            float4 w4 = cw4[i];
            acc4[i].x += xv * w4.x; acc4[i].y += xv * w4.y;
            acc4[i].z += xv * w4.z; acc4[i].w += xv * w4.w;
        }
    }
    int n = n0 + node;
    if (n < NN) {
        const float* accf = (const float*)acc4;
        u32* fout = (u32*)ws + OFF_FBF + (size_t)n * 96 + (cbase >> 1);
#pragma unroll
        for (int i = 0; i < 28; ++i) {
            int col = cbase + 2 * i;
            if (col < 192) {
                fout[i] = f2bf(accf[2 * i]) | (f2bf(accf[2 * i + 1]) << 16);
            } else if (col < 216) {
                float v0 = accf[2 * i];     v0 = v0 > 0.f ? v0 : 0.2f * v0;
                float v1 = accf[2 * i + 1]; v1 = v1 > 0.f ? v1 : 0.2f * v1;
                ws[OFF_EP + (size_t)n * 24 + (col - 192)] = __expf(v0);
                ws[OFF_EP + (size_t)n * 24 + (col - 192) + 1] = __expf(v1);
            }
        }
    }
}

// layer0 fused softmax+aggregate: one wave per dst, lane = channel c.
// per edge: acc[c] += EP[sn][t][c>>3] * F[sn][t][c]; H[d][c] = ELU(acc/den).
__global__ __launch_bounds__(256) void agg1(const int* __restrict__ wsi, float* __restrict__ ws) {
    int tid = threadIdx.x;
    int d = blockIdx.x * 4 + (tid >> 6);
    int c = tid & 63;
    int h4 = c >> 3;
    int start = wsi[OFF_ROWPTR + d], end = wsi[OFF_ROWPTR + d + 1];
    const u16* fb = (const u16*)((const u32*)ws + OFF_FBF);
    const float* ep = ws + OFF_EP;
    const int* psrc = wsi + OFF_PSRC;
    float acc = 0.f, den = 0.f;
    float w_c = 0.f, m_c = 0.f;
    if (start < end) {
        int p = psrc[start];
        int sn = p & 0xFFFFF, t = p >> 20;
        w_c = ep[(size_t)sn * 24 + t * 8 + h4];
        m_c = bf2f(fb[((size_t)sn * 3 + t) * 64 + c]);
    }
    for (int s = start; s < end; ++s) {
        float w = w_c, m = m_c;
        if (s + 1 < end) {
            int p = psrc[s + 1];
            int sn = p & 0xFFFFF, t = p >> 20;
            w_c = ep[(size_t)sn * 24 + t * 8 + h4];
            m_c = bf2f(fb[((size_t)sn * 3 + t) * 64 + c]);
        }
        den += w;
        acc += w * m;
    }
    float dn = (end > start) ? den : 1.f;
    float v = acc / dn;
    v = v > 0.f ? v : __expf(v) - 1.f;  // ELU
    ws[OFF_H + (size_t)d * 64 + c] = v;
}

// F2[n][t][c] = H[n].W2[t][:,c] (bf16), EG[n][t] = exp(leaky(H[n].c2[t])),
// R[n][c] = H[n].res_w[:,c] summed per block into OPART.
// 68 staged cols: 0..47 F2, 48..50 EG logits, 51..66 R, 67 dummy.
__global__ __launch_bounds__(256) void gemm_f2(const float* __restrict__ W2, const float* __restrict__ res_w,
                        float* __restrict__ ws) {
    __shared__ alignas(16) float CW[64 * 68];  // 17.4 KB
    __shared__ alignas(16) float Hs[64 * 65];  // 16.6 KB
    __shared__ float Rs[64][17];
    int tid = threadIdx.x;
    int n0 = blockIdx.x * 64;
    for (int q = tid; q < 4352; q += 256) {
        int k = q / 68, c = q - k * 68;
        float v;
        if (c < 48) v = W2[(c >> 4) * 1024 + k * 16 + (c & 15)];
        else if (c < 51) v = ws[OFF_C2 + (c - 48) * 64 + k];
        else if (c < 67) v = res_w[k * 16 + (c - 51)];
        else v = 0.f;
        CW[k * 68 + c] = v;
    }
    {
        const float4* hg = (const float4*)(ws + OFF_H + (size_t)n0 * 64);
        for (int q = tid; q < 1024; q += 256) {
            int row = q >> 4;
            float4 v = (n0 + row < NN) ? hg[q] : make_float4(0.f, 0.f, 0.f, 0.f);
            *(float4*)(Hs + row * 65 + (q & 15) * 4) = v;
        }
    }
    __syncthreads();
    int node = tid >> 2, cb = tid & 3;
    int cbase = cb * 17;
    float acc[17];
#pragma unroll
    for (int i = 0; i < 17; ++i) acc[i] = 0.f;
    const float* hrow = Hs + node * 65;
    for (int k = 0; k < 64; ++k) {
        float hv = hrow[k];
        const float* cwk = CW + k * 68 + cbase;
#pragma unroll
        for (int i = 0; i < 17; ++i) acc[i] += hv * cwk[i];
    }
    int n = n0 + node;
    u16* f2out = (u16*)((u32*)ws + OFF_F2);
#pragma unroll
    for (int i = 0; i < 17; ++i) {
        int col = cbase + i;
        if (col < 48) {
            if (n < NN) f2out[(size_t)n * 48 + col] = (u16)f2bf(acc[i]);
        } else if (col < 51) {
            if (n < NN) {
                float v = acc[i]; v = v > 0.f ? v : 0.2f * v;
                ws[OFF_EG + (size_t)n * 3 + (col - 48)] = __expf(v);
            }
        } else if (col < 67) {
            Rs[node][col - 51] = acc[i];  // rows >= NN are zero -> safe
        }
    }
    __syncthreads();
    if (tid < 16) {
        float s = 0.f;
#pragma unroll 8
        for (int r = 0; r < 64; ++r) s += Rs[r][tid];
        atomicAdd(ws + OFF_OPART + (blockIdx.x & 63) * 16 + tid, s);
    }
}

// layer1 fused: one wave per dst, 4 edges in parallel (q = lane>>4, c = lane&15).
__global__ __launch_bounds__(256) void agg2(const int* __restrict__ wsi, float* __restrict__ ws) {
    __shared__ float outs[4][16];
    int tid = threadIdx.x;
    int wave = tid >> 6, lane = tid & 63;
    int q = lane >> 4, c = lane & 15;
    int d = blockIdx.x * 4 + wave;
    int start = wsi[OFF_ROWPTR + d], end = wsi[OFF_ROWPTR + d + 1];
    const u16* f2 = (const u16*)((const u32*)ws + OFF_F2);
    const float* eg = ws + OFF_EG;
    const int* psrc = wsi + OFF_PSRC;
    float acc = 0.f, den = 0.f;
    int s = start + q;
    float w_c = 0.f, m_c = 0.f;
    bool valid = s < end;
    if (valid) {
        int p = psrc[s];
        int sn = p & 0xFFFFF, t = p >> 20;
        w_c = eg[(size_t)sn * 3 + t];
        m_c = bf2f(f2[((size_t)sn * 3 + t) * 16 + c]);
    }
    while (valid) {
        float w = w_c, m = m_c;
        int s2 = s + 4;
        bool v2 = s2 < end;
        if (v2) {
            int p = psrc[s2];
            int sn = p & 0xFFFFF, t = p >> 20;
            w_c = eg[(size_t)sn * 3 + t];
            m_c = bf2f(f2[((size_t)sn * 3 + t) * 16 + c]);
        }
        den += w;
        acc += w * m;
        s = s2; valid = v2;
    }
    acc += __shfl_xor(acc, 16);
    acc += __shfl_xor(acc, 32);
    den += __shfl_xor(den, 16);
    den += __shfl_xor(den, 32);
    float val = (end > start) ? acc / den : 0.f;
    if (q == 0) outs[wave][c] = val;
    __syncthreads();
    if (tid < 16) {
        float sum = outs[0][tid] + outs[1][tid] + outs[2][tid] + outs[3][tid];
        atomicAdd(ws + OFF_OPART + (blockIdx.x & 63) * 16 + tid, sum);
    }
}

__global__ void final_k(const float* __restrict__ res_b, float* __restrict__ ws, float* __restrict__ out) {
    int c = threadIdx.x;
    if (c < 16) {
        float s = 0.f;
        for (int r = 0; r < 64; ++r) s += ws[OFF_OPART + r * 16 + c];
        out[c] = s * (1.0f / (float)NN) + res_b[c];
    }
}

extern "C" void kernel_launch(void* const* d_in, const int* in_sizes, int n_in,
                              void* d_out, int out_size, void* d_ws, size_t ws_size,
                              hipStream_t stream) {
    const float* x     = (const float*)d_in[0];
    const int*   src   = (const int*)d_in[1];
    const int*   dst   = (const int*)d_in[2];
    // d_in[3] = ntype (unused by reference)
    const int*   etype = (const int*)d_in[4];
    const float* W1    = (const float*)d_in[5];
    const float* al1   = (const float*)d_in[6];
    const float* ar1   = (const float*)d_in[7];
    const float* W2    = (const float*)d_in[8];
    const float* al2   = (const float*)d_in[9];
    const float* ar2   = (const float*)d_in[10];
    const float* res_w = (const float*)d_in[11];
    const float* res_b = (const float*)d_in[12];
    float* ws = (float*)d_ws;
    int* wsi = (int*)d_ws;
    float* out = (float*)d_out;

    hipLaunchKernelGGL(zero_k, dim3(196), dim3(256), 0, stream, wsi, ws);
    hipLaunchKernelGGL(precompute, dim3(TT), dim3(512), 0, stream, W1, al1, ar1, W2, al2, ar2, ws);
    hipLaunchKernelGGL(hist_k, dim3((EE + 255) / 256), dim3(256), 0, stream, dst, wsi);
    hipLaunchKernelGGL(scan1, dim3(196), dim3(256), 0, stream, wsi);
    hipLaunchKernelGGL(scan2, dim3(1), dim3(256), 0, stream, wsi);
    hipLaunchKernelGGL(scan3, dim3(196), dim3(256), 0, stream, wsi);
    hipLaunchKernelGGL(scatter_k, dim3((EE + 255) / 256), dim3(256), 0, stream, src, dst, etype, wsi);
    hipLaunchKernelGGL(gemm_f, dim3((NN + 63) / 64), dim3(256), 0, stream, x, W1, ws);
    hipLaunchKernelGGL(agg1, dim3(NN / 4), dim3(256), 0, stream, wsi, ws);
    hipLaunchKernelGGL(gemm_f2, dim3((NN + 63) / 64), dim3(256), 0, stream, W2, res_w, ws);
    hipLaunchKernelGGL(agg2, dim3(NN / 4), dim3(256), 0, stream, wsi, ws);
    hipLaunchKernelGGL(final_k, dim3(1), dim3(64), 0, stream, res_b, ws, out);
}

// Round 8
// 406.457 us; speedup vs baseline: 2.1510x; 1.0097x over previous
//
#include <hip/hip_runtime.h>
#include <hip/hip_bf16.h>

typedef unsigned int u32;
typedef unsigned short u16;

#define NN 50000
#define EE 800000
#define TT 3

// ws layout (dword offsets) — total 8,503,016 dwords = 34.0 MiB
#define OFF_C1     0         // 1536 f
#define OFF_C2     1536      // 192 f
#define OFF_CNT    1728      // 50000 i (zeroed each call)
#define OFF_ROWPTR 51728     // 50004 i
#define OFF_CNT2   101732    // 50000 i
#define OFF_BSUM   151732    // 256 i
#define OFF_FLAG   151988    // 4 i (zeroed each call)
#define OFF_PSRC   151992    // 800000 i (src | etype<<20, dst-sorted)
#define OFF_FFP8   951992    // N*48 dw (192 fp8 per node: [t][c])
#define OFF_EPB    3351992   // N*12 dw (24 bf16 per node: [t][h])
#define OFF_F2     3951992   // N*24 dw (48 bf16 per node)
#define OFF_EG     5151992   // N*3 f
#define OFF_H      5301992   // N*64 f
#define OFF_OPART  8501992   // 64*16 f (zeroed each call)

__device__ __forceinline__ float bf2f(u32 u) {
    union { u32 i; float f; } v; v.i = u << 16; return v.f;
}
__device__ __forceinline__ u32 f2bf(float f) {  // RNE
    union { float f; u32 i; } v; v.f = f;
    return (v.i + 0x7fffu + ((v.i >> 16) & 1u)) >> 16;
}

__global__ __launch_bounds__(256) void zero_k(int* wsi, float* ws) {
    int i = blockIdx.x * 256 + threadIdx.x;
    if (i < NN) wsi[OFF_CNT + i] = 0;
    if (i < 1024) ws[OFF_OPART + i] = 0.f;
    if (i == 1024) wsi[OFF_FLAG] = 0;
}

// C1[t][k][h] = sum_k2 W1[t][k][k2] * sum_j (al1+ar1)[t][k2][h*8+j]
// c2[t][k]   = sum_k2 W2[t][k][k2] * sum_j (al2+ar2)[t][k2][j]
__global__ void precompute(const float* __restrict__ W1, const float* __restrict__ al1,
                           const float* __restrict__ ar1, const float* __restrict__ W2,
                           const float* __restrict__ al2, const float* __restrict__ ar2,
                           float* __restrict__ ws) {
    __shared__ float a1c[64][8];
    __shared__ float a2c[16];
    int t = blockIdx.x;
    int tid = threadIdx.x;
    {
        int k2 = tid >> 3, hh = tid & 7;
        float s = 0.f;
#pragma unroll
        for (int j = 0; j < 8; ++j) {
            int idx = t * 4096 + k2 * 64 + hh * 8 + j;
            s += al1[idx] + ar1[idx];
        }
        a1c[k2][hh] = s;
    }
    if (tid < 16) {
        float s = 0.f;
#pragma unroll
        for (int j = 0; j < 16; ++j) {
            int idx = t * 256 + tid * 16 + j;
            s += al2[idx] + ar2[idx];
        }
        a2c[tid] = s;
    }
    __syncthreads();
    {
        int k = tid >> 3, hh = tid & 7;
        float s = 0.f;
#pragma unroll
        for (int k2 = 0; k2 < 64; ++k2)
            s += W1[t * 4096 + k * 64 + k2] * a1c[k2][hh];
        ws[OFF_C1 + t * 512 + k * 8 + hh] = s;
    }
    if (tid < 64) {
        float s = 0.f;
#pragma unroll
        for (int k2 = 0; k2 < 16; ++k2)
            s += W2[t * 1024 + tid * 16 + k2] * a2c[k2];
        ws[OFF_C2 + t * 64 + tid] = s;
    }
}

__global__ __launch_bounds__(256) void hist_k(const int* __restrict__ dst, int* wsi) {
    int e = blockIdx.x * 256 + threadIdx.x;
    if (e < EE) atomicAdd(wsi + OFF_CNT + dst[e], 1);
}

// fused scan1+scan2: per-block reduce -> BSUM; last block scans BSUM (exclusive).
// Cross-XCD handoff via atomics only (G16).
__global__ __launch_bounds__(256) void scan12(int* wsi) {
    __shared__ int sd[256];
    __shared__ bool last;
    int t = threadIdx.x;
    int i = blockIdx.x * 256 + t;
    int v = (i < NN) ? wsi[OFF_CNT + i] : 0;
    sd[t] = v;
    __syncthreads();
    for (int o = 128; o > 0; o >>= 1) {
        if (t < o) sd[t] += sd[t + o];
        __syncthreads();
    }
    if (t == 0) {
        atomicExch(wsi + OFF_BSUM + blockIdx.x, sd[0]);
        __threadfence();
        int done = atomicAdd(wsi + OFF_FLAG, 1);
        last = (done == 195);
    }
    __syncthreads();
    if (!last) return;
    int bv = (t < 196) ? atomicAdd(wsi + OFF_BSUM + t, 0) : 0;
    __syncthreads();
    sd[t] = bv;
    __syncthreads();
    for (int o = 1; o < 256; o <<= 1) {
        int u = (t >= o) ? sd[t - o] : 0;
        __syncthreads();
        sd[t] += u;
        __syncthreads();
    }
    wsi[OFF_BSUM + t] = sd[t] - bv;  // exclusive; scan3 is a new dispatch -> visible
    if (t == 0) wsi[OFF_ROWPTR + NN] = EE;
}

__global__ __launch_bounds__(256) void scan3(int* wsi) {
    __shared__ int sd[256];
    int t = threadIdx.x;
    int i = blockIdx.x * 256 + t;
    int v = (i < NN) ? wsi[OFF_CNT + i] : 0;
    sd[t] = v;
    __syncthreads();
    for (int o = 1; o < 256; o <<= 1) {
        int u = (t >= o) ? sd[t - o] : 0;
        __syncthreads();
        sd[t] += u;
        __syncthreads();
    }
    if (i < NN) {
        int ex = wsi[OFF_BSUM + blockIdx.x] + sd[t] - v;
        wsi[OFF_ROWPTR + i] = ex;
        wsi[OFF_CNT2 + i] = ex;
    }
}

__global__ __launch_bounds__(256) void scatter_k(const int* __restrict__ src, const int* __restrict__ dst,
                          const int* __restrict__ etype, int* wsi) {
    int e = blockIdx.x * 256 + threadIdx.x;
    if (e >= EE) return;
    int d = dst[e];
    int slot = atomicAdd(wsi + OFF_CNT2 + d, 1);
    wsi[OFF_PSRC + slot] = src[e] | (etype[e] << 20);
}

// F[n][t][c] = x[n].W1[t][:,c] stored fp8-e4m3; EP[n][t*8+h] = exp(leaky(x[n].C1[t][:,h])) bf16.
// 224 staged cols: 0..191 F, 192..215 EP logits, 216..223 dummy.
// Thread layout: ng = tid>>3 (2 nodes), cg = tid&7 (28 cols).
__global__ __launch_bounds__(256) void gemm_f(const float* __restrict__ x, const float* __restrict__ W1,
                       float* __restrict__ ws) {
    __shared__ alignas(16) float CW[64 * 224];  // 57.3 KB
    __shared__ alignas(16) float Xs[64 * 65];   // 16.6 KB
    int tid = threadIdx.x;
    int n0 = blockIdx.x * 64;
    for (int q = tid; q < 14336; q += 256) {
        int k = q / 224, c = q - k * 224;
        float v;
        if (c < 192) v = W1[(c >> 6) * 4096 + k * 64 + (c & 63)];
        else if (c < 216) v = ws[OFF_C1 + ((c - 192) >> 3) * 512 + k * 8 + ((c - 192) & 7)];
        else v = 0.f;
        CW[k * 224 + c] = v;
    }
    {
        const float4* xg = (const float4*)(x + (size_t)n0 * 64);
        for (int q = tid; q < 1024; q += 256) {
            int row = q >> 4;
            float4 v = (n0 + row < NN) ? xg[q] : make_float4(0.f, 0.f, 0.f, 0.f);
            *(float4*)(Xs + row * 65 + (q & 15) * 4) = v;
        }
    }
    __syncthreads();
    int ng = tid >> 3, cg = tid & 7;
    int cbase = cg * 28;
    float acc0[28], acc1[28];
#pragma unroll
    for (int i = 0; i < 28; ++i) { acc0[i] = 0.f; acc1[i] = 0.f; }
    const float* x0 = Xs + (2 * ng) * 65;
    const float* x1 = x0 + 65;
    for (int k = 0; k < 64; ++k) {
        float a = x0[k], b = x1[k];
        const float4* cw4 = (const float4*)(CW + k * 224 + cbase);
#pragma unroll
        for (int i = 0; i < 7; ++i) {
            float4 w4 = cw4[i];
            acc0[4*i+0] += a * w4.x; acc0[4*i+1] += a * w4.y;
            acc0[4*i+2] += a * w4.z; acc0[4*i+3] += a * w4.w;
            acc1[4*i+0] += b * w4.x; acc1[4*i+1] += b * w4.y;
            acc1[4*i+2] += b * w4.z; acc1[4*i+3] += b * w4.w;
        }
    }
#pragma unroll
    for (int j = 0; j < 2; ++j) {
        int n = n0 + 2 * ng + j;
        if (n < NN) {
            const float* accf = j ? acc1 : acc0;
            u32* frow = (u32*)ws + OFF_FFP8 + (size_t)n * 48;
            u32* eprow = (u32*)ws + OFF_EPB + (size_t)n * 12;
#pragma unroll
            for (int g = 0; g < 7; ++g) {
                int col = cbase + 4 * g;
                float v0 = accf[4*g], v1 = accf[4*g+1], v2 = accf[4*g+2], v3 = accf[4*g+3];
                if (col < 192) {
                    int dw = __builtin_amdgcn_cvt_pk_fp8_f32(v0, v1, 0, false);
                    dw = __builtin_amdgcn_cvt_pk_fp8_f32(v2, v3, dw, true);
                    frow[cg * 7 + g] = (u32)dw;
                } else if (col < 216) {
                    int jj = col - 192;
                    v0 = v0 > 0.f ? v0 : 0.2f * v0;
                    v1 = v1 > 0.f ? v1 : 0.2f * v1;
                    v2 = v2 > 0.f ? v2 : 0.2f * v2;
                    v3 = v3 > 0.f ? v3 : 0.2f * v3;
                    eprow[(jj >> 1)]     = f2bf(__expf(v0)) | (f2bf(__expf(v1)) << 16);
                    eprow[(jj >> 1) + 1] = f2bf(__expf(v2)) | (f2bf(__expf(v3)) << 16);
                }
            }
        }
    }
}

// layer0 fused softmax+aggregate: one wave per dst, lane = channel c.
// per edge: w = EP[sn][t][c>>3] (bf16), m = F[sn][t][c] (fp8); H[d][c] = ELU(acc/den).
__global__ __launch_bounds__(256) void agg1(const int* __restrict__ wsi, float* __restrict__ ws) {
    int tid = threadIdx.x;
    int d = blockIdx.x * 4 + (tid >> 6);
    int c = tid & 63;
    int h4 = c >> 3;
    int dwF = c >> 2, shF = (c & 3) * 8;
    int sh_ep = (h4 & 1) * 16;
    int epw = h4 >> 1;
    int start = wsi[OFF_ROWPTR + d], end = wsi[OFF_ROWPTR + d + 1];
    const u32* fb = (const u32*)ws + OFF_FFP8;
    const u32* ep = (const u32*)ws + OFF_EPB;
    const int* psrc = wsi + OFF_PSRC;
    float acc = 0.f, den = 0.f;
    u32 fdw_c = 0, epdw_c = 0;
    if (start < end) {
        int p = psrc[start];
        int sn = p & 0xFFFFF, t = p >> 20;
        fdw_c = fb[((size_t)sn * 3 + t) * 16 + dwF];
        epdw_c = ep[(size_t)sn * 12 + t * 4 + epw];
    }
    for (int s = start; s < end; ++s) {
        u32 fdw = fdw_c, epdw = epdw_c;
        if (s + 1 < end) {
            int p = psrc[s + 1];
            int sn = p & 0xFFFFF, t = p >> 20;
            fdw_c = fb[((size_t)sn * 3 + t) * 16 + dwF];
            epdw_c = ep[(size_t)sn * 12 + t * 4 + epw];
        }
        float w = bf2f((epdw >> sh_ep) & 0xffffu);
        float m = __builtin_amdgcn_cvt_f32_fp8((int)(fdw >> shF), 0);
        den += w;
        acc += w * m;
    }
    float dn = (end > start) ? den : 1.f;
    float v = acc / dn;
    v = v > 0.f ? v : __expf(v) - 1.f;  // ELU
    ws[OFF_H + (size_t)d * 64 + c] = v;
}

// F2[n][t][c] = H[n].W2[t][:,c] (bf16), EG[n][t] = exp(leaky(H[n].c2[t])),
// R[n][c] = H[n].res_w[:,c] summed per block into OPART.
// 68 staged cols: 0..47 F2, 48..50 EG logits, 51..66 R, 67 dummy.
__global__ __launch_bounds__(256) void gemm_f2(const float* __restrict__ W2, const float* __restrict__ res_w,
                        float* __restrict__ ws) {
    __shared__ alignas(16) float CW[64 * 68];
    __shared__ alignas(16) float Hs[64 * 65];
    __shared__ float Rs[64][17];
    int tid = threadIdx.x;
    int n0 = blockIdx.x * 64;
    for (int q = tid; q < 4352; q += 256) {
        int k = q / 68, c = q - k * 68;
        float v;
        if (c < 48) v = W2[(c >> 4) * 1024 + k * 16 + (c & 15)];
        else if (c < 51) v = ws[OFF_C2 + (c - 48) * 64 + k];
        else if (c < 67) v = res_w[k * 16 + (c - 51)];
        else v = 0.f;
        CW[k * 68 + c] = v;
    }
    {
        const float4* hg = (const float4*)(ws + OFF_H + (size_t)n0 * 64);
        for (int q = tid; q < 1024; q += 256) {
            int row = q >> 4;
            float4 v = (n0 + row < NN) ? hg[q] : make_float4(0.f, 0.f, 0.f, 0.f);
            *(float4*)(Hs + row * 65 + (q & 15) * 4) = v;
        }
    }
    __syncthreads();
    int node = tid >> 2, cb = tid & 3;
    int cbase = cb * 17;
    float acc[17];
#pragma unroll
    for (int i = 0; i < 17; ++i) acc[i] = 0.f;
    const float* hrow = Hs + node * 65;
    for (int k = 0; k < 64; ++k) {
        float hv = hrow[k];
        const float* cwk = CW + k * 68 + cbase;
#pragma unroll
        for (int i = 0; i < 17; ++i) acc[i] += hv * cwk[i];
    }
    int n = n0 + node;
    u16* f2out = (u16*)((u32*)ws + OFF_F2);
#pragma unroll
    for (int i = 0; i < 17; ++i) {
        int col = cbase + i;
        if (col < 48) {
            if (n < NN) f2out[(size_t)n * 48 + col] = (u16)f2bf(acc[i]);
        } else if (col < 51) {
            if (n < NN) {
                float v = acc[i]; v = v > 0.f ? v : 0.2f * v;
                ws[OFF_EG + (size_t)n * 3 + (col - 48)] = __expf(v);
            }
        } else if (col < 67) {
            Rs[node][col - 51] = acc[i];  // rows >= NN are zero -> safe
        }
    }
    __syncthreads();
    if (tid < 16) {
        float s = 0.f;
#pragma unroll 8
        for (int r = 0; r < 64; ++r) s += Rs[r][tid];
        atomicAdd(ws + OFF_OPART + (blockIdx.x & 63) * 16 + tid, s);
    }
}

// layer1 fused: one wave per dst, 4 edges in parallel (q = lane>>4, c = lane&15).
__global__ __launch_bounds__(256) void agg2(const int* __restrict__ wsi, float* __restrict__ ws) {
    __shared__ float outs[4][16];
    int tid = threadIdx.x;
    int wave = tid >> 6, lane = tid & 63;
    int q = lane >> 4, c = lane & 15;
    int d = blockIdx.x * 4 + wave;
    int start = wsi[OFF_ROWPTR + d], end = wsi[OFF_ROWPTR + d + 1];
    const u16* f2 = (const u16*)((const u32*)ws + OFF_F2);
    const float* eg = ws + OFF_EG;
    const int* psrc = wsi + OFF_PSRC;
    float acc = 0.f, den = 0.f;
    int s = start + q;
    float w_c = 0.f, m_c = 0.f;
    bool valid = s < end;
    if (valid) {
        int p = psrc[s];
        int sn = p & 0xFFFFF, t = p >> 20;
        w_c = eg[(size_t)sn * 3 + t];
        m_c = bf2f(f2[((size_t)sn * 3 + t) * 16 + c]);
    }
    while (valid) {
        float w = w_c, m = m_c;
        int s2 = s + 4;
        bool v2 = s2 < end;
        if (v2) {
            int p = psrc[s2];
            int sn = p & 0xFFFFF, t = p >> 20;
            w_c = eg[(size_t)sn * 3 + t];
            m_c = bf2f(f2[((size_t)sn * 3 + t) * 16 + c]);
        }
        den += w;
        acc += w * m;
        s = s2; valid = v2;
    }
    acc += __shfl_xor(acc, 16);
    acc += __shfl_xor(acc, 32);
    den += __shfl_xor(den, 16);
    den += __shfl_xor(den, 32);
    float val = (end > start) ? acc / den : 0.f;
    if (q == 0) outs[wave][c] = val;
    __syncthreads();
    if (tid < 16) {
        float sum = outs[0][tid] + outs[1][tid] + outs[2][tid] + outs[3][tid];
        atomicAdd(ws + OFF_OPART + (blockIdx.x & 63) * 16 + tid, sum);
    }
}

__global__ void final_k(const float* __restrict__ res_b, float* __restrict__ ws, float* __restrict__ out) {
    int c = threadIdx.x;
    if (c < 16) {
        float s = 0.f;
        for (int r = 0; r < 64; ++r) s += ws[OFF_OPART + r * 16 + c];
        out[c] = s * (1.0f / (float)NN) + res_b[c];
    }
}

extern "C" void kernel_launch(void* const* d_in, const int* in_sizes, int n_in,
                              void* d_out, int out_size, void* d_ws, size_t ws_size,
                              hipStream_t stream) {
    const float* x     = (const float*)d_in[0];
    const int*   src   = (const int*)d_in[1];
    const int*   dst   = (const int*)d_in[2];
    // d_in[3] = ntype (unused by reference)
    const int*   etype = (const int*)d_in[4];
    const float* W1    = (const float*)d_in[5];
    const float* al1   = (const float*)d_in[6];
    const float* ar1   = (const float*)d_in[7];
    const float* W2    = (const float*)d_in[8];
    const float* al2   = (const float*)d_in[9];
    const float* ar2   = (const float*)d_in[10];
    const float* res_w = (const float*)d_in[11];
    const float* res_b = (const float*)d_in[12];
    float* ws = (float*)d_ws;
    int* wsi = (int*)d_ws;
    float* out = (float*)d_out;

    hipLaunchKernelGGL(zero_k, dim3(196), dim3(256), 0, stream, wsi, ws);
    hipLaunchKernelGGL(precompute, dim3(TT), dim3(512), 0, stream, W1, al1, ar1, W2, al2, ar2, ws);
    hipLaunchKernelGGL(hist_k, dim3((EE + 255) / 256), dim3(256), 0, stream, dst, wsi);
    hipLaunchKernelGGL(scan12, dim3(196), dim3(256), 0, stream, wsi);
    hipLaunchKernelGGL(scan3, dim3(196), dim3(256), 0, stream, wsi);
    hipLaunchKernelGGL(scatter_k, dim3((EE + 255) / 256), dim3(256), 0, stream, src, dst, etype, wsi);
    hipLaunchKernelGGL(gemm_f, dim3((NN + 63) / 64), dim3(256), 0, stream, x, W1, ws);
    hipLaunchKernelGGL(agg1, dim3(NN / 4), dim3(256), 0, stream, wsi, ws);
    hipLaunchKernelGGL(gemm_f2, dim3((NN + 63) / 64), dim3(256), 0, stream, W2, res_w, ws);
    hipLaunchKernelGGL(agg2, dim3(NN / 4), dim3(256), 0, stream, wsi, ws);
    hipLaunchKernelGGL(final_k, dim3(1), dim3(64), 0, stream, res_b, ws, out);
}

// Round 12
// 402.161 us; speedup vs baseline: 2.1740x; 1.0107x over previous
//
#include <hip/hip_runtime.h>
#include <hip/hip_bf16.h>

typedef unsigned int u32;
typedef unsigned short u16;

#define NN 50000
#define EE 800000
#define TT 3

// ws layout (dword offsets) — total 8,503,016 dwords = 34.0 MiB
#define OFF_C1     0         // 1536 f
#define OFF_C2     1536      // 192 f
#define OFF_CNT    1728      // 50000 i (memset-zeroed)
#define OFF_FLAG   51728     // 2 i (memset-zeroed, unused)
#define OFF_OPART  51732     // 1024 f (memset-zeroed)
#define OFF_ROWPTR 52756     // 50004 i
#define OFF_CNT2   102760    // 50000 i
#define OFF_BSUM   152760    // 256 i
#define OFF_PSRC   153016    // 800000 i (src | etype<<20, dst-sorted)
#define OFF_FFP8   953016    // N*48 dw (192 fp8 per node: [t][c])
#define OFF_EPB    3353016   // N*12 dw (24 bf16 per node: [t][h])
#define OFF_F2     3953016   // N*24 dw (48 bf16 per node)
#define OFF_EG     5153016   // N*3 f
#define OFF_H      5303016   // N*64 f
// memset range: dword 1728 .. 52755 (CNT+FLAG+OPART) = 51028 dwords

__device__ __forceinline__ float bf2f(u32 u) {
    union { u32 i; float f; } v; v.i = u << 16; return v.f;
}
__device__ __forceinline__ u32 f2bf(float f) {  // RNE
    union { float f; u32 i; } v; v.f = f;
    return (v.i + 0x7fffu + ((v.i >> 16) & 1u)) >> 16;
}

// C1[t][k][h] = sum_k2 W1[t][k][k2] * sum_j (al1+ar1)[t][k2][h*8+j]
// c2[t][k]   = sum_k2 W2[t][k][k2] * sum_j (al2+ar2)[t][k2][j]
__global__ void precompute(const float* __restrict__ W1, const float* __restrict__ al1,
                           const float* __restrict__ ar1, const float* __restrict__ W2,
                           const float* __restrict__ al2, const float* __restrict__ ar2,
                           float* __restrict__ ws) {
    __shared__ float a1c[64][8];
    __shared__ float a2c[16];
    int t = blockIdx.x;
    int tid = threadIdx.x;
    {
        int k2 = tid >> 3, hh = tid & 7;
        float s = 0.f;
#pragma unroll
        for (int j = 0; j < 8; ++j) {
            int idx = t * 4096 + k2 * 64 + hh * 8 + j;
            s += al1[idx] + ar1[idx];
        }
        a1c[k2][hh] = s;
    }
    if (tid < 16) {
        float s = 0.f;
#pragma unroll
        for (int j = 0; j < 16; ++j) {
            int idx = t * 256 + tid * 16 + j;
            s += al2[idx] + ar2[idx];
        }
        a2c[tid] = s;
    }
    __syncthreads();
    {
        int k = tid >> 3, hh = tid & 7;
        float s = 0.f;
#pragma unroll
        for (int k2 = 0; k2 < 64; ++k2)
            s += W1[t * 4096 + k * 64 + k2] * a1c[k2][hh];
        ws[OFF_C1 + t * 512 + k * 8 + hh] = s;
    }
    if (tid < 64) {
        float s = 0.f;
#pragma unroll
        for (int k2 = 0; k2 < 16; ++k2)
            s += W2[t * 1024 + tid * 16 + k2] * a2c[k2];
        ws[OFF_C2 + t * 64 + tid] = s;
    }
}

__global__ __launch_bounds__(256) void hist_k(const int* __restrict__ dst, int* wsi) {
    int e = blockIdx.x * 256 + threadIdx.x;
    if (e < EE) atomicAdd(wsi + OFF_CNT + dst[e], 1);
}

__global__ __launch_bounds__(256) void scan1(int* wsi) {
    __shared__ int sd[256];
    int t = threadIdx.x;
    int i = blockIdx.x * 256 + t;
    int v = (i < NN) ? wsi[OFF_CNT + i] : 0;
    sd[t] = v;
    __syncthreads();
    for (int o = 128; o > 0; o >>= 1) {
        if (t < o) sd[t] += sd[t + o];
        __syncthreads();
    }
    if (t == 0) wsi[OFF_BSUM + blockIdx.x] = sd[0];
}

__global__ __launch_bounds__(256) void scan2(int* wsi) {
    __shared__ int sd[256];
    int t = threadIdx.x;
    int v = (t < 196) ? wsi[OFF_BSUM + t] : 0;
    sd[t] = v;
    __syncthreads();
    for (int o = 1; o < 256; o <<= 1) {
        int u = (t >= o) ? sd[t - o] : 0;
        __syncthreads();
        sd[t] += u;
        __syncthreads();
    }
    wsi[OFF_BSUM + t] = sd[t] - v;  // exclusive
    if (t == 0) wsi[OFF_ROWPTR + NN] = EE;
}

__global__ __launch_bounds__(256) void scan3(int* wsi) {
    __shared__ int sd[256];
    int t = threadIdx.x;
    int i = blockIdx.x * 256 + t;
    int v = (i < NN) ? wsi[OFF_CNT + i] : 0;
    sd[t] = v;
    __syncthreads();
    for (int o = 1; o < 256; o <<= 1) {
        int u = (t >= o) ? sd[t - o] : 0;
        __syncthreads();
        sd[t] += u;
        __syncthreads();
    }
    if (i < NN) {
        int ex = wsi[OFF_BSUM + blockIdx.x] + sd[t] - v;
        wsi[OFF_ROWPTR + i] = ex;
        wsi[OFF_CNT2 + i] = ex;
    }
}

__global__ __launch_bounds__(256) void scatter_k(const int* __restrict__ src, const int* __restrict__ dst,
                          const int* __restrict__ etype, int* wsi) {
    int e = blockIdx.x * 256 + threadIdx.x;
    if (e >= EE) return;
    int d = dst[e];
    int slot = atomicAdd(wsi + OFF_CNT2 + d, 1);
    wsi[OFF_PSRC + slot] = src[e] | (etype[e] << 20);
}

// F[n][t][c] = x[n].W1[t][:,c] stored fp8-e4m3; EP[n][t*8+h] = exp(leaky(x[n].C1[t][:,h])) bf16.
__global__ __launch_bounds__(256) void gemm_f(const float* __restrict__ x, const float* __restrict__ W1,
                       float* __restrict__ ws) {
    __shared__ alignas(16) float CW[64 * 224];
    __shared__ alignas(16) float Xs[64 * 65];
    int tid = threadIdx.x;
    int n0 = blockIdx.x * 64;
    for (int q = tid; q < 14336; q += 256) {
        int k = q / 224, c = q - k * 224;
        float v;
        if (c < 192) v = W1[(c >> 6) * 4096 + k * 64 + (c & 63)];
        else if (c < 216) v = ws[OFF_C1 + ((c - 192) >> 3) * 512 + k * 8 + ((c - 192) & 7)];
        else v = 0.f;
        CW[k * 224 + c] = v;
    }
    {
        const float4* xg = (const float4*)(x + (size_t)n0 * 64);
        for (int q = tid; q < 1024; q += 256) {
            int row = q >> 4;
            float4 v = (n0 + row < NN) ? xg[q] : make_float4(0.f, 0.f, 0.f, 0.f);
            *(float4*)(Xs + row * 65 + (q & 15) * 4) = v;
        }
    }
    __syncthreads();
    int ng = tid >> 3, cg = tid & 7;
    int cbase = cg * 28;
    float acc0[28], acc1[28];
#pragma unroll
    for (int i = 0; i < 28; ++i) { acc0[i] = 0.f; acc1[i] = 0.f; }
    const float* x0 = Xs + (2 * ng) * 65;
    const float* x1 = x0 + 65;
    for (int k = 0; k < 64; ++k) {
        float a = x0[k], b = x1[k];
        const float4* cw4 = (const float4*)(CW + k * 224 + cbase);
#pragma unroll
        for (int i = 0; i < 7; ++i) {
            float4 w4 = cw4[i];
            acc0[4*i+0] += a * w4.x; acc0[4*i+1] += a * w4.y;
            acc0[4*i+2] += a * w4.z; acc0[4*i+3] += a * w4.w;
            acc1[4*i+0] += b * w4.x; acc1[4*i+1] += b * w4.y;
            acc1[4*i+2] += b * w4.z; acc1[4*i+3] += b * w4.w;
        }
    }
#pragma unroll
    for (int j = 0; j < 2; ++j) {
        int n = n0 + 2 * ng + j;
        if (n < NN) {
            const float* accf = j ? acc1 : acc0;
            u32* frow = (u32*)ws + OFF_FFP8 + (size_t)n * 48;
            u32* eprow = (u32*)ws + OFF_EPB + (size_t)n * 12;
#pragma unroll
            for (int g = 0; g < 7; ++g) {
                int col = cbase + 4 * g;
                float v0 = accf[4*g], v1 = accf[4*g+1], v2 = accf[4*g+2], v3 = accf[4*g+3];
                if (col < 192) {
                    int dw = __builtin_amdgcn_cvt_pk_fp8_f32(v0, v1, 0, false);
                    dw = __builtin_amdgcn_cvt_pk_fp8_f32(v2, v3, dw, true);
                    frow[cg * 7 + g] = (u32)dw;
                } else if (col < 216) {
                    int jj = col - 192;
                    v0 = v0 > 0.f ? v0 : 0.2f * v0;
                    v1 = v1 > 0.f ? v1 : 0.2f * v1;
                    v2 = v2 > 0.f ? v2 : 0.2f * v2;
                    v3 = v3 > 0.f ? v3 : 0.2f * v3;
                    eprow[(jj >> 1)]     = f2bf(__expf(v0)) | (f2bf(__expf(v1)) << 16);
                    eprow[(jj >> 1) + 1] = f2bf(__expf(v2)) | (f2bf(__expf(v3)) << 16);
                }
            }
        }
    }
}

// layer0 fused softmax+aggregate — r7-proven body (sequential 1-deep pointer-chase).
__global__ __launch_bounds__(256) void agg1(const int* __restrict__ wsi, float* __restrict__ ws) {
    int tid = threadIdx.x;
    int d = blockIdx.x * 4 + (tid >> 6);
    int c = tid & 63;
    int h4 = c >> 3;
    int dwF = c >> 2, shF = (c & 3) * 8;
    int sh_ep = (h4 & 1) * 16;
    int epw = h4 >> 1;
    int start = wsi[OFF_ROWPTR + d], end = wsi[OFF_ROWPTR + d + 1];
    const u32* fb = (const u32*)ws + OFF_FFP8;
    const u32* ep = (const u32*)ws + OFF_EPB;
    const int* psrc = wsi + OFF_PSRC;
    float acc = 0.f, den = 0.f;
    u32 fdw_c = 0, epdw_c = 0;
    if (start < end) {
        int p = psrc[start];
        int sn = p & 0xFFFFF, t = p >> 20;
        fdw_c = fb[((size_t)sn * 3 + t) * 16 + dwF];
        epdw_c = ep[(size_t)sn * 12 + t * 4 + epw];
    }
    for (int s = start; s < end; ++s) {
        u32 fdw = fdw_c, epdw = epdw_c;
        if (s + 1 < end) {
            int p = psrc[s + 1];
            int sn = p & 0xFFFFF, t = p >> 20;
            fdw_c = fb[((size_t)sn * 3 + t) * 16 + dwF];
            epdw_c = ep[(size_t)sn * 12 + t * 4 + epw];
        }
        float w = bf2f((epdw >> sh_ep) & 0xffffu);
        float m = __builtin_amdgcn_cvt_f32_fp8((int)(fdw >> shF), 0);
        den += w;
        acc += w * m;
    }
    float dn = (end > start) ? den : 1.f;
    float v = acc / dn;
    v = v > 0.f ? v : __expf(v) - 1.f;  // ELU
    ws[OFF_H + (size_t)d * 64 + c] = v;
}

// F2[n][t][c] = H[n].W2[t][:,c] (bf16), EG[n][t] = exp(leaky(H[n].c2[t])),
// R[n][c] = H[n].res_w[:,c] summed per block into OPART.
__global__ __launch_bounds__(256) void gemm_f2(const float* __restrict__ W2, const float* __restrict__ res_w,
                        float* __restrict__ ws) {
    __shared__ alignas(16) float CW[64 * 68];
    __shared__ alignas(16) float Hs[64 * 65];
    __shared__ float Rs[64][17];
    int tid = threadIdx.x;
    int n0 = blockIdx.x * 64;
    for (int q = tid; q < 4352; q += 256) {
        int k = q / 68, c = q - k * 68;
        float v;
        if (c < 48) v = W2[(c >> 4) * 1024 + k * 16 + (c & 15)];
        else if (c < 51) v = ws[OFF_C2 + (c - 48) * 64 + k];
        else if (c < 67) v = res_w[k * 16 + (c - 51)];
        else v = 0.f;
        CW[k * 68 + c] = v;
    }
    {
        const float4* hg = (const float4*)(ws + OFF_H + (size_t)n0 * 64);
        for (int q = tid; q < 1024; q += 256) {
            int row = q >> 4;
            float4 v = (n0 + row < NN) ? hg[q] : make_float4(0.f, 0.f, 0.f, 0.f);
            *(float4*)(Hs + row * 65 + (q & 15) * 4) = v;
        }
    }
    __syncthreads();
    int node = tid >> 2, cb = tid & 3;
    int cbase = cb * 17;
    float acc[17];
#pragma unroll
    for (int i = 0; i < 17; ++i) acc[i] = 0.f;
    const float* hrow = Hs + node * 65;
    for (int k = 0; k < 64; ++k) {
        float hv = hrow[k];
        const float* cwk = CW + k * 68 + cbase;
#pragma unroll
        for (int i = 0; i < 17; ++i) acc[i] += hv * cwk[i];
    }
    int n = n0 + node;
    u16* f2out = (u16*)((u32*)ws + OFF_F2);
#pragma unroll
    for (int i = 0; i < 17; ++i) {
        int col = cbase + i;
        if (col < 48) {
            if (n < NN) f2out[(size_t)n * 48 + col] = (u16)f2bf(acc[i]);
        } else if (col < 51) {
            if (n < NN) {
                float v = acc[i]; v = v > 0.f ? v : 0.2f * v;
                ws[OFF_EG + (size_t)n * 3 + (col - 48)] = __expf(v);
            }
        } else if (col < 67) {
            Rs[node][col - 51] = acc[i];
        }
    }
    __syncthreads();
    if (tid < 16) {
        float s = 0.f;
#pragma unroll 8
        for (int r = 0; r < 64; ++r) s += Rs[r][tid];
        atomicAdd(ws + OFF_OPART + (blockIdx.x & 63) * 16 + tid, s);
    }
}

// layer1 fused — r7-proven body (strided 4-lane groups, 2-deep pointer-chase).
__global__ __launch_bounds__(256) void agg2(const int* __restrict__ wsi, float* __restrict__ ws) {
    __shared__ float outs[4][16];
    int tid = threadIdx.x;
    int wave = tid >> 6, lane = tid & 63;
    int q = lane >> 4, c = lane & 15;
    int d = blockIdx.x * 4 + wave;
    int start = wsi[OFF_ROWPTR + d], end = wsi[OFF_ROWPTR + d + 1];
    const u16* f2 = (const u16*)((const u32*)ws + OFF_F2);
    const float* eg = ws + OFF_EG;
    const int* psrc = wsi + OFF_PSRC;
    float acc = 0.f, den = 0.f;
    int s = start + q;
    float w_c = 0.f, m_c = 0.f;
    bool valid = s < end;
    if (valid) {
        int p = psrc[s];
        int sn = p & 0xFFFFF, t = p >> 20;
        w_c = eg[(size_t)sn * 3 + t];
        m_c = bf2f(f2[((size_t)sn * 3 + t) * 16 + c]);
    }
    while (valid) {
        float w = w_c, m = m_c;
        int s2 = s + 4;
        bool v2 = s2 < end;
        if (v2) {
            int p = psrc[s2];
            int sn = p & 0xFFFFF, t = p >> 20;
            w_c = eg[(size_t)sn * 3 + t];
            m_c = bf2f(f2[((size_t)sn * 3 + t) * 16 + c]);
        }
        den += w;
        acc += w * m;
        s = s2; valid = v2;
    }
    acc += __shfl_xor(acc, 16);
    acc += __shfl_xor(acc, 32);
    den += __shfl_xor(den, 16);
    den += __shfl_xor(den, 32);
    float val = (end > start) ? acc / den : 0.f;
    if (q == 0) outs[wave][c] = val;
    __syncthreads();
    if (tid < 16) {
        float sum = outs[0][tid] + outs[1][tid] + outs[2][tid] + outs[3][tid];
        atomicAdd(ws + OFF_OPART + (blockIdx.x & 63) * 16 + tid, sum);
    }
}

__global__ void final_k(const float* __restrict__ res_b, float* __restrict__ ws, float* __restrict__ out) {
    int c = threadIdx.x;
    if (c < 16) {
        float s = 0.f;
        for (int r = 0; r < 64; ++r) s += ws[OFF_OPART + r * 16 + c];
        out[c] = s * (1.0f / (float)NN) + res_b[c];
    }
}

extern "C" void kernel_launch(void* const* d_in, const int* in_sizes, int n_in,
                              void* d_out, int out_size, void* d_ws, size_t ws_size,
                              hipStream_t stream) {
    const float* x     = (const float*)d_in[0];
    const int*   src   = (const int*)d_in[1];
    const int*   dst   = (const int*)d_in[2];
    // d_in[3] = ntype (unused by reference)
    const int*   etype = (const int*)d_in[4];
    const float* W1    = (const float*)d_in[5];
    const float* al1   = (const float*)d_in[6];
    const float* ar1   = (const float*)d_in[7];
    const float* W2    = (const float*)d_in[8];
    const float* al2   = (const float*)d_in[9];
    const float* ar2   = (const float*)d_in[10];
    const float* res_w = (const float*)d_in[11];
    const float* res_b = (const float*)d_in[12];
    float* ws = (float*)d_ws;
    int* wsi = (int*)d_ws;
    float* out = (float*)d_out;

    hipMemsetAsync((char*)d_ws + (size_t)OFF_CNT * 4, 0, (size_t)51028 * 4, stream);
    hipLaunchKernelGGL(precompute, dim3(TT), dim3(512), 0, stream, W1, al1, ar1, W2, al2, ar2, ws);
    hipLaunchKernelGGL(hist_k, dim3((EE + 255) / 256), dim3(256), 0, stream, dst, wsi);
    hipLaunchKernelGGL(scan1, dim3(196), dim3(256), 0, stream, wsi);
    hipLaunchKernelGGL(scan2, dim3(1), dim3(256), 0, stream, wsi);
    hipLaunchKernelGGL(scan3, dim3(196), dim3(256), 0, stream, wsi);
    hipLaunchKernelGGL(scatter_k, dim3((EE + 255) / 256), dim3(256), 0, stream, src, dst, etype, wsi);
    hipLaunchKernelGGL(gemm_f, dim3((NN + 63) / 64), dim3(256), 0, stream, x, W1, ws);
    hipLaunchKernelGGL(agg1, dim3(NN / 4), dim3(256), 0, stream, wsi, ws);
    hipLaunchKernelGGL(gemm_f2, dim3((NN + 63) / 64), dim3(256), 0, stream, W2, res_w, ws);
    hipLaunchKernelGGL(agg2, dim3(NN / 4), dim3(256), 0, stream, wsi, ws);
    hipLaunchKernelGGL(final_k, dim3(1), dim3(64), 0, stream, res_b, ws, out);
}

// Round 13
// 399.615 us; speedup vs baseline: 2.1878x; 1.0064x over previous
//
#include <hip/hip_runtime.h>
#include <hip/hip_bf16.h>

typedef unsigned int u32;
typedef unsigned short u16;

#define NN 50000
#define EE 800000
#define TT 3

// ws layout (dword offsets) — total 8,503,016 dwords = 34.0 MiB
#define OFF_C1     0         // 1536 f
#define OFF_C2     1536      // 192 f
#define OFF_CNT    1728      // 50000 i (memset-zeroed)
#define OFF_FLAG   51728     // 2 i (memset-zeroed, unused)
#define OFF_OPART  51732     // 1024 f (memset-zeroed)
#define OFF_ROWPTR 52756     // 50004 i
#define OFF_CNT2   102760    // 50000 i
#define OFF_BSUM   152760    // 256 i
#define OFF_PSRC   153016    // 800000 i (src | etype<<20, dst-sorted)
#define OFF_FFP8   953016    // N*48 dw (192 fp8 per node: [t][c])
#define OFF_EPB    3353016   // N*12 dw (24 bf16 per node: [t][h])
#define OFF_F2     3953016   // N*24 dw (48 bf16 per node)
#define OFF_EG     5153016   // N*3 f
#define OFF_H      5303016   // N*64 f
// memset range: dword 1728 .. 52755 (CNT+FLAG+OPART) = 51028 dwords

__device__ __forceinline__ float bf2f(u32 u) {
    union { u32 i; float f; } v; v.i = u << 16; return v.f;
}
__device__ __forceinline__ u32 f2bf(float f) {  // RNE
    union { float f; u32 i; } v; v.f = f;
    return (v.i + 0x7fffu + ((v.i >> 16) & 1u)) >> 16;
}

// C1[t][k][h] = sum_k2 W1[t][k][k2] * sum_j (al1+ar1)[t][k2][h*8+j]
// c2[t][k]   = sum_k2 W2[t][k][k2] * sum_j (al2+ar2)[t][k2][j]
__global__ void precompute(const float* __restrict__ W1, const float* __restrict__ al1,
                           const float* __restrict__ ar1, const float* __restrict__ W2,
                           const float* __restrict__ al2, const float* __restrict__ ar2,
                           float* __restrict__ ws) {
    __shared__ float a1c[64][8];
    __shared__ float a2c[16];
    int t = blockIdx.x;
    int tid = threadIdx.x;
    {
        int k2 = tid >> 3, hh = tid & 7;
        float s = 0.f;
#pragma unroll
        for (int j = 0; j < 8; ++j) {
            int idx = t * 4096 + k2 * 64 + hh * 8 + j;
            s += al1[idx] + ar1[idx];
        }
        a1c[k2][hh] = s;
    }
    if (tid < 16) {
        float s = 0.f;
#pragma unroll
        for (int j = 0; j < 16; ++j) {
            int idx = t * 256 + tid * 16 + j;
            s += al2[idx] + ar2[idx];
        }
        a2c[tid] = s;
    }
    __syncthreads();
    {
        int k = tid >> 3, hh = tid & 7;
        float s = 0.f;
#pragma unroll
        for (int k2 = 0; k2 < 64; ++k2)
            s += W1[t * 4096 + k * 64 + k2] * a1c[k2][hh];
        ws[OFF_C1 + t * 512 + k * 8 + hh] = s;
    }
    if (tid < 64) {
        float s = 0.f;
#pragma unroll
        for (int k2 = 0; k2 < 16; ++k2)
            s += W2[t * 1024 + tid * 16 + k2] * a2c[k2];
        ws[OFF_C2 + t * 64 + tid] = s;
    }
}

__global__ __launch_bounds__(256) void hist_k(const int* __restrict__ dst, int* wsi) {
    int e = blockIdx.x * 256 + threadIdx.x;
    if (e < EE) atomicAdd(wsi + OFF_CNT + dst[e], 1);
}

__global__ __launch_bounds__(256) void scan1(int* wsi) {
    __shared__ int sd[256];
    int t = threadIdx.x;
    int i = blockIdx.x * 256 + t;
    int v = (i < NN) ? wsi[OFF_CNT + i] : 0;
    sd[t] = v;
    __syncthreads();
    for (int o = 128; o > 0; o >>= 1) {
        if (t < o) sd[t] += sd[t + o];
        __syncthreads();
    }
    if (t == 0) wsi[OFF_BSUM + blockIdx.x] = sd[0];
}

__global__ __launch_bounds__(256) void scan2(int* wsi) {
    __shared__ int sd[256];
    int t = threadIdx.x;
    int v = (t < 196) ? wsi[OFF_BSUM + t] : 0;
    sd[t] = v;
    __syncthreads();
    for (int o = 1; o < 256; o <<= 1) {
        int u = (t >= o) ? sd[t - o] : 0;
        __syncthreads();
        sd[t] += u;
        __syncthreads();
    }
    wsi[OFF_BSUM + t] = sd[t] - v;  // exclusive
    if (t == 0) wsi[OFF_ROWPTR + NN] = EE;
}

__global__ __launch_bounds__(256) void scan3(int* wsi) {
    __shared__ int sd[256];
    int t = threadIdx.x;
    int i = blockIdx.x * 256 + t;
    int v = (i < NN) ? wsi[OFF_CNT + i] : 0;
    sd[t] = v;
    __syncthreads();
    for (int o = 1; o < 256; o <<= 1) {
        int u = (t >= o) ? sd[t - o] : 0;
        __syncthreads();
        sd[t] += u;
        __syncthreads();
    }
    if (i < NN) {
        int ex = wsi[OFF_BSUM + blockIdx.x] + sd[t] - v;
        wsi[OFF_ROWPTR + i] = ex;
        wsi[OFF_CNT2 + i] = ex;
    }
}

__global__ __launch_bounds__(256) void scatter_k(const int* __restrict__ src, const int* __restrict__ dst,
                          const int* __restrict__ etype, int* wsi) {
    int e = blockIdx.x * 256 + threadIdx.x;
    if (e >= EE) return;
    int d = dst[e];
    int slot = atomicAdd(wsi + OFF_CNT2 + d, 1);
    wsi[OFF_PSRC + slot] = src[e] | (etype[e] << 20);
}

// F[n][t][c] = x[n].W1[t][:,c] stored fp8-e4m3; EP[n][t*8+h] = exp(leaky(x[n].C1[t][:,h])) bf16.
__global__ __launch_bounds__(256) void gemm_f(const float* __restrict__ x, const float* __restrict__ W1,
                       float* __restrict__ ws) {
    __shared__ alignas(16) float CW[64 * 224];
    __shared__ alignas(16) float Xs[64 * 65];
    int tid = threadIdx.x;
    int n0 = blockIdx.x * 64;
    for (int q = tid; q < 14336; q += 256) {
        int k = q / 224, c = q - k * 224;
        float v;
        if (c < 192) v = W1[(c >> 6) * 4096 + k * 64 + (c & 63)];
        else if (c < 216) v = ws[OFF_C1 + ((c - 192) >> 3) * 512 + k * 8 + ((c - 192) & 7)];
        else v = 0.f;
        CW[k * 224 + c] = v;
    }
    {
        const float4* xg = (const float4*)(x + (size_t)n0 * 64);
        for (int q = tid; q < 1024; q += 256) {
            int row = q >> 4;
            float4 v = (n0 + row < NN) ? xg[q] : make_float4(0.f, 0.f, 0.f, 0.f);
            *(float4*)(Xs + row * 65 + (q & 15) * 4) = v;
        }
    }
    __syncthreads();
    int ng = tid >> 3, cg = tid & 7;
    int cbase = cg * 28;
    float acc0[28], acc1[28];
#pragma unroll
    for (int i = 0; i < 28; ++i) { acc0[i] = 0.f; acc1[i] = 0.f; }
    const float* x0 = Xs + (2 * ng) * 65;
    const float* x1 = x0 + 65;
    for (int k = 0; k < 64; ++k) {
        float a = x0[k], b = x1[k];
        const float4* cw4 = (const float4*)(CW + k * 224 + cbase);
#pragma unroll
        for (int i = 0; i < 7; ++i) {
            float4 w4 = cw4[i];
            acc0[4*i+0] += a * w4.x; acc0[4*i+1] += a * w4.y;
            acc0[4*i+2] += a * w4.z; acc0[4*i+3] += a * w4.w;
            acc1[4*i+0] += b * w4.x; acc1[4*i+1] += b * w4.y;
            acc1[4*i+2] += b * w4.z; acc1[4*i+3] += b * w4.w;
        }
    }
#pragma unroll
    for (int j = 0; j < 2; ++j) {
        int n = n0 + 2 * ng + j;
        if (n < NN) {
            const float* accf = j ? acc1 : acc0;
            u32* frow = (u32*)ws + OFF_FFP8 + (size_t)n * 48;
            u32* eprow = (u32*)ws + OFF_EPB + (size_t)n * 12;
#pragma unroll
            for (int g = 0; g < 7; ++g) {
                int col = cbase + 4 * g;
                float v0 = accf[4*g], v1 = accf[4*g+1], v2 = accf[4*g+2], v3 = accf[4*g+3];
                if (col < 192) {
                    int dw = __builtin_amdgcn_cvt_pk_fp8_f32(v0, v1, 0, false);
                    dw = __builtin_amdgcn_cvt_pk_fp8_f32(v2, v3, dw, true);
                    frow[cg * 7 + g] = (u32)dw;
                } else if (col < 216) {
                    int jj = col - 192;
                    v0 = v0 > 0.f ? v0 : 0.2f * v0;
                    v1 = v1 > 0.f ? v1 : 0.2f * v1;
                    v2 = v2 > 0.f ? v2 : 0.2f * v2;
                    v3 = v3 > 0.f ? v3 : 0.2f * v3;
                    eprow[(jj >> 1)]     = f2bf(__expf(v0)) | (f2bf(__expf(v1)) << 16);
                    eprow[(jj >> 1) + 1] = f2bf(__expf(v2)) | (f2bf(__expf(v3)) << 16);
                }
            }
        }
    }
}

// layer0 fused softmax+aggregate: TWO waves per dst (stride-2 edge interleave),
// r12-proven inner loop body, LDS combine of partial acc/den.
__global__ __launch_bounds__(256) void agg1(const int* __restrict__ wsi, float* __restrict__ ws) {
    __shared__ float pacc[4][64];
    __shared__ float pden[4][64];
    int tid = threadIdx.x;
    int wave = tid >> 6;       // 0..3: waves 0,1 -> dst0; waves 2,3 -> dst1
    int lane = tid & 63;
    int half = wave & 1;
    int d = blockIdx.x * 2 + (wave >> 1);
    int c = lane;
    int h4 = c >> 3;
    int dwF = c >> 2, shF = (c & 3) * 8;
    int sh_ep = (h4 & 1) * 16;
    int epw = h4 >> 1;
    int start = wsi[OFF_ROWPTR + d], end = wsi[OFF_ROWPTR + d + 1];
    const u32* fb = (const u32*)ws + OFF_FFP8;
    const u32* ep = (const u32*)ws + OFF_EPB;
    const int* psrc = wsi + OFF_PSRC;
    float acc = 0.f, den = 0.f;
    int s0 = start + half;
    u32 fdw_c = 0, epdw_c = 0;
    if (s0 < end) {
        int p = psrc[s0];
        int sn = p & 0xFFFFF, t = p >> 20;
        fdw_c = fb[((size_t)sn * 3 + t) * 16 + dwF];
        epdw_c = ep[(size_t)sn * 12 + t * 4 + epw];
    }
    for (int s = s0; s < end; s += 2) {
        u32 fdw = fdw_c, epdw = epdw_c;
        if (s + 2 < end) {
            int p = psrc[s + 2];
            int sn = p & 0xFFFFF, t = p >> 20;
            fdw_c = fb[((size_t)sn * 3 + t) * 16 + dwF];
            epdw_c = ep[(size_t)sn * 12 + t * 4 + epw];
        }
        float w = bf2f((epdw >> sh_ep) & 0xffffu);
        float m = __builtin_amdgcn_cvt_f32_fp8((int)(fdw >> shF), 0);
        den += w;
        acc += w * m;
    }
    pacc[wave][lane] = acc;
    pden[wave][lane] = den;
    __syncthreads();
    if (half == 0) {
        float at = pacc[wave][lane] + pacc[wave + 1][lane];
        float dt = pden[wave][lane] + pden[wave + 1][lane];
        float dn = (end > start) ? dt : 1.f;
        float v = at / dn;
        v = v > 0.f ? v : __expf(v) - 1.f;  // ELU
        ws[OFF_H + (size_t)d * 64 + c] = v;
    }
}

// F2[n][t][c] = H[n].W2[t][:,c] (bf16), EG[n][t] = exp(leaky(H[n].c2[t])),
// R[n][c] = H[n].res_w[:,c] summed per block into OPART.
__global__ __launch_bounds__(256) void gemm_f2(const float* __restrict__ W2, const float* __restrict__ res_w,
                        float* __restrict__ ws) {
    __shared__ alignas(16) float CW[64 * 68];
    __shared__ alignas(16) float Hs[64 * 65];
    __shared__ float Rs[64][17];
    int tid = threadIdx.x;
    int n0 = blockIdx.x * 64;
    for (int q = tid; q < 4352; q += 256) {
        int k = q / 68, c = q - k * 68;
        float v;
        if (c < 48) v = W2[(c >> 4) * 1024 + k * 16 + (c & 15)];
        else if (c < 51) v = ws[OFF_C2 + (c - 48) * 64 + k];
        else if (c < 67) v = res_w[k * 16 + (c - 51)];
        else v = 0.f;
        CW[k * 68 + c] = v;
    }
    {
        const float4* hg = (const float4*)(ws + OFF_H + (size_t)n0 * 64);
        for (int q = tid; q < 1024; q += 256) {
            int row = q >> 4;
            float4 v = (n0 + row < NN) ? hg[q] : make_float4(0.f, 0.f, 0.f, 0.f);
            *(float4*)(Hs + row * 65 + (q & 15) * 4) = v;
        }
    }
    __syncthreads();
    int node = tid >> 2, cb = tid & 3;
    int cbase = cb * 17;
    float acc[17];
#pragma unroll
    for (int i = 0; i < 17; ++i) acc[i] = 0.f;
    const float* hrow = Hs + node * 65;
    for (int k = 0; k < 64; ++k) {
        float hv = hrow[k];
        const float* cwk = CW + k * 68 + cbase;
#pragma unroll
        for (int i = 0; i < 17; ++i) acc[i] += hv * cwk[i];
    }
    int n = n0 + node;
    u16* f2out = (u16*)((u32*)ws + OFF_F2);
#pragma unroll
    for (int i = 0; i < 17; ++i) {
        int col = cbase + i;
        if (col < 48) {
            if (n < NN) f2out[(size_t)n * 48 + col] = (u16)f2bf(acc[i]);
        } else if (col < 51) {
            if (n < NN) {
                float v = acc[i]; v = v > 0.f ? v : 0.2f * v;
                ws[OFF_EG + (size_t)n * 3 + (col - 48)] = __expf(v);
            }
        } else if (col < 67) {
            Rs[node][col - 51] = acc[i];
        }
    }
    __syncthreads();
    if (tid < 16) {
        float s = 0.f;
#pragma unroll 8
        for (int r = 0; r < 64; ++r) s += Rs[r][tid];
        atomicAdd(ws + OFF_OPART + (blockIdx.x & 63) * 16 + tid, s);
    }
}

// layer1 fused — r7-proven body (strided 4-lane groups, 2-deep pointer-chase).
__global__ __launch_bounds__(256) void agg2(const int* __restrict__ wsi, float* __restrict__ ws) {
    __shared__ float outs[4][16];
    int tid = threadIdx.x;
    int wave = tid >> 6, lane = tid & 63;
    int q = lane >> 4, c = lane & 15;
    int d = blockIdx.x * 4 + wave;
    int start = wsi[OFF_ROWPTR + d], end = wsi[OFF_ROWPTR + d + 1];
    const u16* f2 = (const u16*)((const u32*)ws + OFF_F2);
    const float* eg = ws + OFF_EG;
    const int* psrc = wsi + OFF_PSRC;
    float acc = 0.f, den = 0.f;
    int s = start + q;
    float w_c = 0.f, m_c = 0.f;
    bool valid = s < end;
    if (valid) {
        int p = psrc[s];
        int sn = p & 0xFFFFF, t = p >> 20;
        w_c = eg[(size_t)sn * 3 + t];
        m_c = bf2f(f2[((size_t)sn * 3 + t) * 16 + c]);
    }
    while (valid) {
        float w = w_c, m = m_c;
        int s2 = s + 4;
        bool v2 = s2 < end;
        if (v2) {
            int p = psrc[s2];
            int sn = p & 0xFFFFF, t = p >> 20;
            w_c = eg[(size_t)sn * 3 + t];
            m_c = bf2f(f2[((size_t)sn * 3 + t) * 16 + c]);
        }
        den += w;
        acc += w * m;
        s = s2; valid = v2;
    }
    acc += __shfl_xor(acc, 16);
    acc += __shfl_xor(acc, 32);
    den += __shfl_xor(den, 16);
    den += __shfl_xor(den, 32);
    float val = (end > start) ? acc / den : 0.f;
    if (q == 0) outs[wave][c] = val;
    __syncthreads();
    if (tid < 16) {
        float sum = outs[0][tid] + outs[1][tid] + outs[2][tid] + outs[3][tid];
        atomicAdd(ws + OFF_OPART + (blockIdx.x & 63) * 16 + tid, sum);
    }
}

__global__ void final_k(const float* __restrict__ res_b, float* __restrict__ ws, float* __restrict__ out) {
    int c = threadIdx.x;
    if (c < 16) {
        float s = 0.f;
        for (int r = 0; r < 64; ++r) s += ws[OFF_OPART + r * 16 + c];
        out[c] = s * (1.0f / (float)NN) + res_b[c];
    }
}

extern "C" void kernel_launch(void* const* d_in, const int* in_sizes, int n_in,
                              void* d_out, int out_size, void* d_ws, size_t ws_size,
                              hipStream_t stream) {
    const float* x     = (const float*)d_in[0];
    const int*   src   = (const int*)d_in[1];
    const int*   dst   = (const int*)d_in[2];
    // d_in[3] = ntype (unused by reference)
    const int*   etype = (const int*)d_in[4];
    const float* W1    = (const float*)d_in[5];
    const float* al1   = (const float*)d_in[6];
    const float* ar1   = (const float*)d_in[7];
    const float* W2    = (const float*)d_in[8];
    const float* al2   = (const float*)d_in[9];
    const float* ar2   = (const float*)d_in[10];
    const float* res_w = (const float*)d_in[11];
    const float* res_b = (const float*)d_in[12];
    float* ws = (float*)d_ws;
    int* wsi = (int*)d_ws;
    float* out = (float*)d_out;

    hipMemsetAsync((char*)d_ws + (size_t)OFF_CNT * 4, 0, (size_t)51028 * 4, stream);
    hipLaunchKernelGGL(precompute, dim3(TT), dim3(512), 0, stream, W1, al1, ar1, W2, al2, ar2, ws);
    hipLaunchKernelGGL(hist_k, dim3((EE + 255) / 256), dim3(256), 0, stream, dst, wsi);
    hipLaunchKernelGGL(scan1, dim3(196), dim3(256), 0, stream, wsi);
    hipLaunchKernelGGL(scan2, dim3(1), dim3(256), 0, stream, wsi);
    hipLaunchKernelGGL(scan3, dim3(196), dim3(256), 0, stream, wsi);
    hipLaunchKernelGGL(scatter_k, dim3((EE + 255) / 256), dim3(256), 0, stream, src, dst, etype, wsi);
    hipLaunchKernelGGL(gemm_f, dim3((NN + 63) / 64), dim3(256), 0, stream, x, W1, ws);
    hipLaunchKernelGGL(agg1, dim3(NN / 2), dim3(256), 0, stream, wsi, ws);
    hipLaunchKernelGGL(gemm_f2, dim3((NN + 63) / 64), dim3(256), 0, stream, W2, res_w, ws);
    hipLaunchKernelGGL(agg2, dim3(NN / 4), dim3(256), 0, stream, wsi, ws);
    hipLaunchKernelGGL(final_k, dim3(1), dim3(64), 0, stream, res_b, ws, out);
}